// Round 1
// baseline (2361.676 us; speedup 1.0000x reference)
//
#include <hip/hip_runtime.h>
#include <math.h>

#define T_STEPS 8
#define NNODES 10000
#define NFEAT 16
#define NEDGES 320000
#define HDIM 64
#define LDIM 3

__device__ __forceinline__ float sigmoidf_(float x){ return 1.f/(1.f+__expf(-x)); }
__device__ __forceinline__ float softplusf_(float x){ return fmaxf(x,0.f)+log1pf(__expf(-fabsf(x))); }
__device__ __forceinline__ float tanhf_(float x){ return 2.f*sigmoidf_(2.f*x)-1.f; }

// ---------------- setup kernels (once per call) ----------------

__global__ void __launch_bounds__(256) k_init(
    const float* __restrict__ init_lice, const float* __restrict__ at_w1,
    const float* __restrict__ gru_wih, const float* __restrict__ gru_whh,
    const float* __restrict__ en_w2, const float* __restrict__ de_w1,
    float* __restrict__ h, float* __restrict__ lice,
    float* __restrict__ at_w1T, float* __restrict__ wihT, float* __restrict__ whhT,
    float* __restrict__ enw2T, float* __restrict__ dew1T,
    int* __restrict__ counts)
{
    int i = blockIdx.x*256 + threadIdx.x;              // 0 .. 639999
    if (i < NNODES*HDIM) h[i] = 0.f;
    if (i < NNODES*LDIM) lice[i] = init_lice[i];
    if (i < NNODES) counts[i] = 0;
    if (i < 128*HDIM){ int k = i>>6, j = i&63; at_w1T[i] = at_w1[j*128+k]; }      // (128,64)
    if (i < 72*192){ int k = i/192, j = i%192; wihT[i] = gru_wih[j*72+k]; }       // (72,192)
    if (i < 64*192){ int k = i/192, j = i%192; whhT[i] = gru_whh[j*64+k]; }       // (64,192)
    if (i < 64*64){ int k = i>>6, j = i&63; enw2T[i] = en_w2[j*64+k]; }           // (64,64)
    if (i < 64*64){ int k = i>>6, j = i&63; dew1T[i] = de_w1[j*64+k]; }           // (64,64)
}

__global__ void __launch_bounds__(256) k_hist(const int* __restrict__ ei_dst, int* __restrict__ counts){
    int e = blockIdx.x*256 + threadIdx.x;
    if (e < NEDGES) atomicAdd(&counts[ei_dst[e]], 1);
}

__global__ void __launch_bounds__(1024) k_scan(const int* __restrict__ counts,
                                               int* __restrict__ rowptr, int* __restrict__ cursor){
    __shared__ int sums[1024];
    int t = threadIdx.x;
    const int CH = 10;                      // 1000 threads x 10 = 10000
    int c0 = t*CH;
    int s = 0;
    if (c0 < NNODES){
        #pragma unroll
        for (int i=0;i<CH;i++) s += counts[c0+i];
    }
    sums[t] = s;
    __syncthreads();
    for (int off=1; off<1024; off<<=1){
        int v = (t>=off) ? sums[t-off] : 0;
        __syncthreads();
        sums[t] += v;
        __syncthreads();
    }
    if (c0 < NNODES){
        int run = (t==0) ? 0 : sums[t-1];
        for (int i=0;i<CH;i++){ rowptr[c0+i] = run; run += counts[c0+i]; cursor[c0+i] = 0; }
        if (t == (NNODES/CH)-1) rowptr[NNODES] = run;
    }
}

__global__ void __launch_bounds__(256) k_scatter(const int* __restrict__ ei_dst,
        const int* __restrict__ rowptr, int* __restrict__ cursor, int* __restrict__ perm){
    int e = blockIdx.x*256 + threadIdx.x;
    if (e >= NEDGES) return;
    int d = ei_dst[e];
    int pos = rowptr[d] + atomicAdd(&cursor[d], 1);
    perm[pos] = e;
}

// ---------------- per-step kernel 1: edge MLPs -> logits ----------------
// thread-per-edge; weights via wave-uniform (scalar) loads; register arrays static-indexed.

__global__ void __launch_bounds__(256) k_edge_logits(
    const float* __restrict__ xt, const float* __restrict__ h,
    const int* __restrict__ ei_src,
    const float* __restrict__ dist, const float* __restrict__ dirn,
    const float* __restrict__ ee_w1, const float* __restrict__ ee_b1,
    const float* __restrict__ ee_w2, const float* __restrict__ ee_b2,
    const float* __restrict__ at_w1T, const float* __restrict__ at_b1,
    const float* __restrict__ at_w2, const float* __restrict__ at_b2,
    float* __restrict__ logits)
{
    int e = blockIdx.x*256 + threadIdx.x;
    int src = ei_src[e];
    float d  = dist[e];
    float u  = xt[src*NFEAT+13];
    float v  = xt[src*NFEAT+14];
    float flux = u*dirn[e*2+0] + v*dirn[e*2+1];
    float wflux = fmaxf(flux, 0.f) * __expf(-d*(1.f/15.f));
    float a0 = d, a1 = wflux, a2 = xt[src*NFEAT+11], a3 = xt[src*NFEAT+12];

    // ee layer 1 (4 -> 64), relu
    float h1[HDIM];
    #pragma unroll
    for (int k=0;k<HDIM;++k){
        float s = ee_b1[k] + a0*ee_w1[k*4+0] + a1*ee_w1[k*4+1] + a2*ee_w1[k*4+2] + a3*ee_w1[k*4+3];
        h1[k] = fmaxf(s, 0.f);
    }
    // attention hidden accumulators, init with bias
    float ah[HDIM];
    #pragma unroll
    for (int j=0;j<HDIM;++j) ah[j] = at_b1[j];

    // ee layer 2 (64 -> 64, no relu) fused with scatter into attention layer 1 (ef half)
    #pragma unroll 1
    for (int k=0;k<HDIM;++k){
        float efk = ee_b2[k];
        #pragma unroll
        for (int m=0;m<HDIM;++m) efk += h1[m]*ee_w2[k*HDIM+m];
        #pragma unroll
        for (int j=0;j<HDIM;++j) ah[j] += efk*at_w1T[k*HDIM+j];
    }
    // h_src half of attention layer 1
    const float* hs = h + src*HDIM;
    #pragma unroll 1
    for (int k=0;k<HDIM;k+=4){
        float4 x4 = *reinterpret_cast<const float4*>(hs + k);
        #pragma unroll
        for (int j=0;j<HDIM;++j) ah[j] += x4.x*at_w1T[(HDIM+k+0)*HDIM+j];
        #pragma unroll
        for (int j=0;j<HDIM;++j) ah[j] += x4.y*at_w1T[(HDIM+k+1)*HDIM+j];
        #pragma unroll
        for (int j=0;j<HDIM;++j) ah[j] += x4.z*at_w1T[(HDIM+k+2)*HDIM+j];
        #pragma unroll
        for (int j=0;j<HDIM;++j) ah[j] += x4.w*at_w1T[(HDIM+k+3)*HDIM+j];
    }
    // attention layer 2 (relu on hidden)
    float logit = at_b2[0];
    #pragma unroll
    for (int j=0;j<HDIM;++j) logit += at_w2[j]*fmaxf(ah[j], 0.f);

    logits[e] = logit + __logf(wflux + 1e-8f);
}

// ---------------- per-step kernel 2: segment softmax + pressure ----------------
// wave-per-dst-node over CSR.

__global__ void __launch_bounds__(256) k_softmax_pressure(
    const float* __restrict__ logits, const float* __restrict__ h,
    const float* __restrict__ lice, const int* __restrict__ ei_src,
    const int* __restrict__ rowptr, const int* __restrict__ perm,
    const float* __restrict__ log_beta,
    float* __restrict__ pressure)
{
    int w = (blockIdx.x*256 + threadIdx.x) >> 6;   // node id
    int lane = threadIdx.x & 63;
    int start = rowptr[w], end = rowptr[w+1];

    float m = -INFINITY;
    for (int i=start+lane; i<end; i+=64) m = fmaxf(m, logits[perm[i]]);
    #pragma unroll
    for (int off=32; off>=1; off>>=1) m = fmaxf(m, __shfl_xor(m, off));

    float s = 0.f;
    for (int i=start+lane; i<end; i+=64) s += __expf(logits[perm[i]] - m);
    #pragma unroll
    for (int off=32; off>=1; off>>=1) s += __shfl_xor(s, off);

    float beta = __expf(log_beta[0]);
    float inv  = 1.f/(s + 1e-8f);

    float p = 0.f;
    for (int i=start; i<end; ++i){
        int e = perm[i];
        int src = ei_src[e];
        float wgt = __expf(logits[e] - m) * inv * lice[src*LDIM] * beta;
        p += wgt * h[src*HDIM + lane];
    }
    pressure[w*HDIM + lane] = p;
}

// ---------------- per-step kernel 3: node update (env enc, fec, GRU, decoder) ----------------
// wave-per-node, lane = feature.

__global__ void __launch_bounds__(256) k_node_update(
    const float* __restrict__ xt,
    float* __restrict__ h, float* __restrict__ lice,
    const float* __restrict__ pressure,
    const float* __restrict__ en_w1, const float* __restrict__ en_b1,
    const float* __restrict__ enw2T, const float* __restrict__ en_b2,
    const float* __restrict__ fe_w1, const float* __restrict__ fe_b1,
    const float* __restrict__ fe_w2, const float* __restrict__ fe_b2,
    const float* __restrict__ fe_w3, const float* __restrict__ fe_b3,
    const float* __restrict__ wihT, const float* __restrict__ whhT,
    const float* __restrict__ gru_bih, const float* __restrict__ gru_bhh,
    const float* __restrict__ dew1T, const float* __restrict__ de_b1,
    const float* __restrict__ de_w2, const float* __restrict__ de_b2,
    const float* __restrict__ temp_sens,
    float* __restrict__ out_t)
{
    const int w = threadIdx.x >> 6;
    const int lane = threadIdx.x & 63;
    const int n = blockIdx.x*4 + w;

    __shared__ float sm_din[4][72];
    __shared__ float sm_h[4][64];
    __shared__ float sm_t[4][64];
    __shared__ float sm_a[4][32];

    const float* xr = xt + n*NFEAT;
    float env0 = xr[11], env1 = xr[12], env2 = xr[13], env3 = xr[14], env4 = xr[15];
    float tn = (env0 - 10.f)*(1.f/5.f);

    // fec hidden a (32), lanes 0..31
    if (lane < 32) sm_a[w][lane] = fmaxf(tn*fe_w1[lane] + fe_b1[lane], 0.f);
    // env enc layer 1 (5 -> 64), relu
    float t1 = en_b1[lane] + env0*en_w1[lane*5+0] + env1*en_w1[lane*5+1]
             + env2*en_w1[lane*5+2] + env3*en_w1[lane*5+3] + env4*en_w1[lane*5+4];
    sm_t[w][lane] = fmaxf(t1, 0.f);
    // stage h row
    sm_h[w][lane] = h[n*HDIM + lane];
    __syncthreads();

    // fec: layer b (32->32 relu) then 32->1, softplus
    float contrib = 0.f;
    if (lane < 32){
        float fb = fe_b2[lane];
        #pragma unroll
        for (int k=0;k<32;++k) fb += sm_a[w][k]*fe_w2[lane*32+k];
        fb = fmaxf(fb, 0.f);
        contrib = fb*fe_w3[lane];
    }
    #pragma unroll
    for (int off=32; off>=1; off>>=1) contrib += __shfl_xor(contrib, off);
    float fec = softplusf_(contrib + fe_b3[0]);

    // env enc layer 2 (64 -> 64, no relu)
    float enc = en_b2[lane];
    #pragma unroll 1
    for (int k=0;k<HDIM;++k) enc += sm_t[w][k]*enw2T[k*HDIM + lane];

    float din_l = enc + pressure[n*HDIM + lane];
    sm_din[w][lane] = din_l;
    if (lane < 5) sm_din[w][64+lane] = xr[11+lane];
    if (lane < 3) sm_din[w][69+lane] = lice[n*LDIM + lane];
    __syncthreads();

    // GRU
    float gi0 = gru_bih[lane], gi1 = gru_bih[64+lane], gi2 = gru_bih[128+lane];
    #pragma unroll 1
    for (int k=0;k<72;++k){
        float x = sm_din[w][k];
        gi0 += x*wihT[k*192 + lane];
        gi1 += x*wihT[k*192 + 64 + lane];
        gi2 += x*wihT[k*192 + 128 + lane];
    }
    float gh0 = gru_bhh[lane], gh1 = gru_bhh[64+lane], gh2 = gru_bhh[128+lane];
    #pragma unroll 1
    for (int k=0;k<64;++k){
        float x = sm_h[w][k];
        gh0 += x*whhT[k*192 + lane];
        gh1 += x*whhT[k*192 + 64 + lane];
        gh2 += x*whhT[k*192 + 128 + lane];
    }
    float r  = sigmoidf_(gi0 + gh0);
    float z  = sigmoidf_(gi1 + gh1);
    float nn = tanhf_(gi2 + r*gh2);
    float hold = sm_h[w][lane];
    float hnew = (1.f - z)*nn + z*hold;
    h[n*HDIM + lane] = hnew;
    sm_t[w][lane] = hnew;               // sm_t free (readers done before last sync)
    __syncthreads();

    // decoder layer 1 (64 -> 64, relu)
    float d1 = de_b1[lane];
    #pragma unroll 1
    for (int k=0;k<HDIM;++k) d1 += sm_t[w][k]*dew1T[k*HDIM + lane];
    d1 = fmaxf(d1, 0.f);
    sm_din[w][lane] = d1;               // sm_din free (readers done before last sync)
    __syncthreads();

    if (lane < LDIM){
        float o = de_b2[lane];
        #pragma unroll
        for (int k=0;k<HDIM;++k) o += sm_din[w][k]*de_w2[lane*HDIM+k];
        float lb = softplusf_(o);
        float ln = lb * (1.f + temp_sens[0]*(fec - 1.f));
        lice[n*LDIM + lane] = ln;
        out_t[n*LDIM + lane] = ln;
    }
}

// ---------------- launcher ----------------

extern "C" void kernel_launch(void* const* d_in, const int* in_sizes, int n_in,
                              void* d_out, int out_size, void* d_ws, size_t ws_size,
                              hipStream_t stream) {
    const float* nfs       = (const float*)d_in[0];
    const float* init_lice = (const float*)d_in[1];
    const float* dist      = (const float*)d_in[2];
    const float* dirn      = (const float*)d_in[3];
    const float* ee_w1     = (const float*)d_in[4];
    const float* ee_b1     = (const float*)d_in[5];
    const float* ee_w2     = (const float*)d_in[6];
    const float* ee_b2     = (const float*)d_in[7];
    const float* at_w1     = (const float*)d_in[8];
    const float* at_b1     = (const float*)d_in[9];
    const float* at_w2     = (const float*)d_in[10];
    const float* at_b2     = (const float*)d_in[11];
    const float* en_w1     = (const float*)d_in[12];
    const float* en_b1     = (const float*)d_in[13];
    const float* en_w2     = (const float*)d_in[14];
    const float* en_b2     = (const float*)d_in[15];
    const float* fe_w1     = (const float*)d_in[16];
    const float* fe_b1     = (const float*)d_in[17];
    const float* fe_w2     = (const float*)d_in[18];
    const float* fe_b2     = (const float*)d_in[19];
    const float* fe_w3     = (const float*)d_in[20];
    const float* fe_b3     = (const float*)d_in[21];
    const float* gru_wih   = (const float*)d_in[22];
    const float* gru_whh   = (const float*)d_in[23];
    const float* gru_bih   = (const float*)d_in[24];
    const float* gru_bhh   = (const float*)d_in[25];
    const float* de_w1     = (const float*)d_in[26];
    const float* de_b1     = (const float*)d_in[27];
    const float* de_w2     = (const float*)d_in[28];
    const float* de_b2     = (const float*)d_in[29];
    const float* log_beta  = (const float*)d_in[30];
    const float* temp_sens = (const float*)d_in[31];
    const int*   ei        = (const int*)d_in[32];
    const int*   ei_src = ei;
    const int*   ei_dst = ei + NEDGES;
    float* out = (float*)d_out;

    // workspace carve (floats)
    float* wsf = (float*)d_ws;
    size_t off = 0;
    float* h        = wsf + off; off += (size_t)NNODES*HDIM;   // 640000
    float* lice     = wsf + off; off += (size_t)NNODES*LDIM;   // 30000
    float* logits   = wsf + off; off += (size_t)NEDGES;        // 320000
    float* pressure = wsf + off; off += (size_t)NNODES*HDIM;   // 640000
    float* at_w1T   = wsf + off; off += 128*HDIM;              // 8192
    float* wihT     = wsf + off; off += 72*192;                // 13824
    float* whhT     = wsf + off; off += 64*192;                // 12288
    float* enw2T    = wsf + off; off += 64*64;                 // 4096
    float* dew1T    = wsf + off; off += 64*64;                 // 4096
    int* counts = (int*)(wsf + off); off += NNODES;
    int* rowptr = (int*)(wsf + off); off += NNODES+1;
    int* cursor = (int*)(wsf + off); off += NNODES;
    int* perm   = (int*)(wsf + off); off += NEDGES;

    // setup
    k_init<<<2500,256,0,stream>>>(init_lice, at_w1, gru_wih, gru_whh, en_w2, de_w1,
                                  h, lice, at_w1T, wihT, whhT, enw2T, dew1T, counts);
    k_hist<<<1250,256,0,stream>>>(ei_dst, counts);
    k_scan<<<1,1024,0,stream>>>(counts, rowptr, cursor);
    k_scatter<<<1250,256,0,stream>>>(ei_dst, rowptr, cursor, perm);

    for (int t=0; t<T_STEPS; ++t){
        const float* xt = nfs + (size_t)t*NNODES*NFEAT;
        k_edge_logits<<<1250,256,0,stream>>>(xt, h, ei_src, dist, dirn,
                                             ee_w1, ee_b1, ee_w2, ee_b2,
                                             at_w1T, at_b1, at_w2, at_b2, logits);
        k_softmax_pressure<<<2500,256,0,stream>>>(logits, h, lice, ei_src,
                                                  rowptr, perm, log_beta, pressure);
        k_node_update<<<2500,256,0,stream>>>(xt, h, lice, pressure,
                                             en_w1, en_b1, enw2T, en_b2,
                                             fe_w1, fe_b1, fe_w2, fe_b2, fe_w3, fe_b3,
                                             wihT, whhT, gru_bih, gru_bhh,
                                             dew1T, de_b1, de_w2, de_b2,
                                             temp_sens, out + (size_t)t*NNODES*LDIM);
    }
}

// Round 2
// 1359.048 us; speedup vs baseline: 1.7377x; 1.7377x over previous
//
#include <hip/hip_runtime.h>
#include <math.h>

#define T_STEPS 8
#define NNODES 10000
#define NFEAT 16
#define NEDGES 320000
#define HDIM 64
#define LDIM 3
#define CAP 128

__device__ __forceinline__ float sigmoidf_(float x){ return 1.f/(1.f+__expf(-x)); }
__device__ __forceinline__ float softplusf_(float x){ return fmaxf(x,0.f)+log1pf(__expf(-fabsf(x))); }
__device__ __forceinline__ float tanhf_(float x){ return 2.f*sigmoidf_(2.f*x)-1.f; }

// ---------------- setup kernels (once per call) ----------------

__global__ void __launch_bounds__(256) k_init(
    const float* __restrict__ init_lice,
    const float* __restrict__ gru_wih, const float* __restrict__ gru_whh,
    const float* __restrict__ en_w2, const float* __restrict__ de_w1,
    float* __restrict__ h, float* __restrict__ lice,
    float* __restrict__ wihT, float* __restrict__ whhT,
    float* __restrict__ enw2T, float* __restrict__ dew1T,
    int* __restrict__ counts)
{
    int i = blockIdx.x*256 + threadIdx.x;              // 0 .. 639999
    if (i < NNODES*HDIM) h[i] = 0.f;
    if (i < NNODES*LDIM) lice[i] = init_lice[i];
    if (i < NNODES) counts[i] = 0;
    if (i < 72*192){ int k = i/192, j = i%192; wihT[i] = gru_wih[j*72+k]; }       // (72,192)
    if (i < 64*192){ int k = i/192, j = i%192; whhT[i] = gru_whh[j*64+k]; }       // (64,192)
    if (i < 64*64){ int k = i>>6, j = i&63; enw2T[i] = en_w2[j*64+k]; }           // (64,64)
    if (i < 64*64){ int k = i>>6, j = i&63; dew1T[i] = de_w1[j*64+k]; }           // (64,64)
}

// Collapse ee-layer2 + attention-layer1(ef half): M[m][j] = sum_k ee_w2[k][m]*at_w1[j][k]
// cvec[j] = at_b1[j] + sum_k ee_b2[k]*at_w1[j][k];  A2[m][j] = at_w1[j][64+m]
__global__ void __launch_bounds__(256) k_prep(
    const float* __restrict__ ee_w2, const float* __restrict__ ee_b2,
    const float* __restrict__ at_w1, const float* __restrict__ at_b1,
    float* __restrict__ M, float* __restrict__ A2, float* __restrict__ cvec)
{
    int i = blockIdx.x*256 + threadIdx.x;   // 0..4095
    if (i >= 64*64) return;
    int m = i>>6, j = i&63;
    float acc = 0.f;
    #pragma unroll 8
    for (int k=0;k<64;++k) acc += ee_w2[k*64+m]*at_w1[j*128+k];
    M[i] = acc;
    A2[i] = at_w1[j*128+64+m];
    if (m == 0){
        float c = at_b1[j];
        #pragma unroll 8
        for (int k=0;k<64;++k) c += ee_b2[k]*at_w1[j*128+k];
        cvec[j] = c;
    }
}

__global__ void __launch_bounds__(256) k_hist(const int* __restrict__ ei_dst, int* __restrict__ counts){
    int e = blockIdx.x*256 + threadIdx.x;
    if (e < NEDGES) atomicAdd(&counts[ei_dst[e]], 1);
}

__global__ void __launch_bounds__(1024) k_scan(const int* __restrict__ counts,
                                               int* __restrict__ rowptr, int* __restrict__ cursor){
    __shared__ int sums[1024];
    int t = threadIdx.x;
    const int CH = 10;                      // 1000 threads x 10 = 10000
    int c0 = t*CH;
    int s = 0;
    if (c0 < NNODES){
        #pragma unroll
        for (int i=0;i<CH;i++) s += counts[c0+i];
    }
    sums[t] = s;
    __syncthreads();
    for (int off=1; off<1024; off<<=1){
        int v = (t>=off) ? sums[t-off] : 0;
        __syncthreads();
        sums[t] += v;
        __syncthreads();
    }
    if (c0 < NNODES){
        int run = (t==0) ? 0 : sums[t-1];
        for (int i=0;i<CH;i++){ rowptr[c0+i] = run; run += counts[c0+i]; cursor[c0+i] = 0; }
        if (t == (NNODES/CH)-1) rowptr[NNODES] = run;
    }
}

__global__ void __launch_bounds__(256) k_scatter(const int* __restrict__ ei_dst,
        const int* __restrict__ rowptr, int* __restrict__ cursor, int* __restrict__ perm){
    int e = blockIdx.x*256 + threadIdx.x;
    if (e >= NEDGES) return;
    int d = ei_dst[e];
    int pos = rowptr[d] + atomicAdd(&cursor[d], 1);
    perm[pos] = e;
}

// ---------------- per-step kernel 1: edge MLPs -> logits (collapsed) ----------------
// Per edge: ah[j] = cvec[j] + sum_m relu(h1_m)*M[m][j] + sum_m h_src[m]*A2[m][j]
// Only ONE live 64-float register array (ah); h1_m is transient.

__global__ void __launch_bounds__(256) k_edge_logits(
    const float* __restrict__ xt, const float* __restrict__ h,
    const int* __restrict__ ei_src,
    const float* __restrict__ dist, const float* __restrict__ dirn,
    const float* __restrict__ ee_w1, const float* __restrict__ ee_b1,
    const float* __restrict__ M, const float* __restrict__ A2,
    const float* __restrict__ cvec,
    const float* __restrict__ at_w2, const float* __restrict__ at_b2,
    float* __restrict__ logits)
{
    int e = blockIdx.x*256 + threadIdx.x;
    int src = ei_src[e];
    float d  = dist[e];
    float2 dir2 = *reinterpret_cast<const float2*>(dirn + 2*e);
    float temp = xt[src*NFEAT+11];
    float4 q  = *reinterpret_cast<const float4*>(xt + src*NFEAT + 12); // sal,u,v,(unused)
    float flux = q.y*dir2.x + q.z*dir2.y;
    float wflux = fmaxf(flux, 0.f) * __expf(-d*(1.f/15.f));
    float a0 = d, a1 = wflux, a2 = temp, a3 = q.x;

    float ah[HDIM];
    #pragma unroll
    for (int j=0;j<HDIM;++j) ah[j] = cvec[j];

    const float* hs = h + src*HDIM;
    #pragma unroll 1
    for (int m=0;m<HDIM;m+=4){
        float4 h4 = *reinterpret_cast<const float4*>(hs + m);
        float hm[4] = {h4.x, h4.y, h4.z, h4.w};
        #pragma unroll
        for (int mm=0;mm<4;++mm){
            int mi = m+mm;
            float4 w1 = *reinterpret_cast<const float4*>(ee_w1 + mi*4);   // uniform -> s_load
            float h1m = fmaxf(ee_b1[mi] + a0*w1.x + a1*w1.y + a2*w1.z + a3*w1.w, 0.f);
            #pragma unroll
            for (int j=0;j<HDIM;++j) ah[j] += h1m*M[mi*HDIM+j];
            #pragma unroll
            for (int j=0;j<HDIM;++j) ah[j] += hm[mm]*A2[mi*HDIM+j];
        }
    }
    float logit = at_b2[0];
    #pragma unroll
    for (int j=0;j<HDIM;++j) logit += at_w2[j]*fmaxf(ah[j], 0.f);

    logits[e] = logit + __logf(wflux + 1e-8f);
}

// ---------------- per-step kernel 2: segment softmax + pressure ----------------
// wave-per-dst-node over CSR; per-edge weights precomputed lane-parallel into LDS.

__global__ void __launch_bounds__(256) k_softmax_pressure(
    const float* __restrict__ logits, const float* __restrict__ h,
    const float* __restrict__ lice, const int* __restrict__ ei_src,
    const int* __restrict__ rowptr, const int* __restrict__ perm,
    const float* __restrict__ log_beta,
    float* __restrict__ pressure)
{
    __shared__ float swgt[4][CAP];
    __shared__ int   ssrc[4][CAP];
    const int w = threadIdx.x >> 6;
    const int lane = threadIdx.x & 63;
    const int node = blockIdx.x*4 + w;
    const int start = rowptr[node], end = rowptr[node+1];
    const int deg = end - start;
    const int nfast = deg < CAP ? deg : CAP;

    // pass 1: gather logits/src (cache first CAP in LDS), running max
    float m = -INFINITY;
    for (int i=start+lane; i<end; i+=64){
        int e = perm[i];
        float lg = logits[e];
        int o = i - start;
        if (o < CAP){ swgt[w][o] = lg; ssrc[w][o] = ei_src[e]; }
        m = fmaxf(m, lg);
    }
    #pragma unroll
    for (int off=32; off>=1; off>>=1) m = fmaxf(m, __shfl_xor(m, off));

    // pass 2: sum of exp
    float s = 0.f;
    for (int i=start+lane; i<end; i+=64){
        int o = i - start;
        float lg = (o < CAP) ? swgt[w][o] : logits[perm[i]];
        s += __expf(lg - m);
    }
    #pragma unroll
    for (int off=32; off>=1; off>>=1) s += __shfl_xor(s, off);

    const float beta = __expf(log_beta[0]);
    const float inv  = 1.f/(s + 1e-8f);
    const float binv = beta*inv;

    // pass 3: convert cached logits -> final weights (lane-parallel, same-wave LDS is in-order)
    for (int o=lane; o<nfast; o+=64){
        int sc = ssrc[w][o];
        swgt[w][o] = __expf(swgt[w][o] - m) * binv * lice[sc*LDIM];
    }

    // pass 4: accumulate pressure, 4-way unrolled for loads-in-flight
    float p0=0.f, p1=0.f, p2=0.f, p3=0.f;
    int i = 0;
    for (; i+4<=nfast; i+=4){
        float w0=swgt[w][i+0], w1=swgt[w][i+1], w2=swgt[w][i+2], w3=swgt[w][i+3];
        int   a0=ssrc[w][i+0], a1=ssrc[w][i+1], a2=ssrc[w][i+2], a3=ssrc[w][i+3];
        p0 += w0*h[a0*HDIM+lane];
        p1 += w1*h[a1*HDIM+lane];
        p2 += w2*h[a2*HDIM+lane];
        p3 += w3*h[a3*HDIM+lane];
    }
    for (; i<nfast; ++i) p0 += swgt[w][i]*h[ssrc[w][i]*HDIM+lane];
    // rare slow tail (deg > CAP)
    for (int ii=start+CAP; ii<end; ++ii){
        int e = perm[ii];
        int sc = ei_src[e];
        float wg = __expf(logits[e]-m)*binv*lice[sc*LDIM];
        p0 += wg*h[sc*HDIM+lane];
    }
    pressure[node*HDIM + lane] = (p0+p1)+(p2+p3);
}

// ---------------- per-step kernel 3: node update (env enc, fec, GRU, decoder) ----------------
// wave-per-node, lane = feature.

__global__ void __launch_bounds__(256) k_node_update(
    const float* __restrict__ xt,
    float* __restrict__ h, float* __restrict__ lice,
    const float* __restrict__ pressure,
    const float* __restrict__ en_w1, const float* __restrict__ en_b1,
    const float* __restrict__ enw2T, const float* __restrict__ en_b2,
    const float* __restrict__ fe_w1, const float* __restrict__ fe_b1,
    const float* __restrict__ fe_w2, const float* __restrict__ fe_b2,
    const float* __restrict__ fe_w3, const float* __restrict__ fe_b3,
    const float* __restrict__ wihT, const float* __restrict__ whhT,
    const float* __restrict__ gru_bih, const float* __restrict__ gru_bhh,
    const float* __restrict__ dew1T, const float* __restrict__ de_b1,
    const float* __restrict__ de_w2, const float* __restrict__ de_b2,
    const float* __restrict__ temp_sens,
    float* __restrict__ out_t)
{
    const int w = threadIdx.x >> 6;
    const int lane = threadIdx.x & 63;
    const int n = blockIdx.x*4 + w;

    __shared__ float sm_din[4][72];
    __shared__ float sm_h[4][64];
    __shared__ float sm_t[4][64];
    __shared__ float sm_a[4][32];

    const float* xr = xt + n*NFEAT;
    float env0 = xr[11], env1 = xr[12], env2 = xr[13], env3 = xr[14], env4 = xr[15];
    float tn = (env0 - 10.f)*(1.f/5.f);

    // fec hidden a (32), lanes 0..31
    if (lane < 32) sm_a[w][lane] = fmaxf(tn*fe_w1[lane] + fe_b1[lane], 0.f);
    // env enc layer 1 (5 -> 64), relu
    float t1 = en_b1[lane] + env0*en_w1[lane*5+0] + env1*en_w1[lane*5+1]
             + env2*en_w1[lane*5+2] + env3*en_w1[lane*5+3] + env4*en_w1[lane*5+4];
    sm_t[w][lane] = fmaxf(t1, 0.f);
    // stage h row
    sm_h[w][lane] = h[n*HDIM + lane];
    __syncthreads();

    // fec: layer b (32->32 relu) then 32->1, softplus
    float contrib = 0.f;
    if (lane < 32){
        float fb = fe_b2[lane];
        #pragma unroll
        for (int k=0;k<32;++k) fb += sm_a[w][k]*fe_w2[lane*32+k];
        fb = fmaxf(fb, 0.f);
        contrib = fb*fe_w3[lane];
    }
    #pragma unroll
    for (int off=32; off>=1; off>>=1) contrib += __shfl_xor(contrib, off);
    float fec = softplusf_(contrib + fe_b3[0]);

    // env enc layer 2 (64 -> 64, no relu)
    float enc = en_b2[lane];
    #pragma unroll 4
    for (int k=0;k<HDIM;++k) enc += sm_t[w][k]*enw2T[k*HDIM + lane];

    float din_l = enc + pressure[n*HDIM + lane];
    sm_din[w][lane] = din_l;
    if (lane < 5) sm_din[w][64+lane] = xr[11+lane];
    if (lane < 3) sm_din[w][69+lane] = lice[n*LDIM + lane];
    __syncthreads();

    // GRU
    float gi0 = gru_bih[lane], gi1 = gru_bih[64+lane], gi2 = gru_bih[128+lane];
    #pragma unroll 4
    for (int k=0;k<72;++k){
        float x = sm_din[w][k];
        gi0 += x*wihT[k*192 + lane];
        gi1 += x*wihT[k*192 + 64 + lane];
        gi2 += x*wihT[k*192 + 128 + lane];
    }
    float gh0 = gru_bhh[lane], gh1 = gru_bhh[64+lane], gh2 = gru_bhh[128+lane];
    #pragma unroll 4
    for (int k=0;k<64;++k){
        float x = sm_h[w][k];
        gh0 += x*whhT[k*192 + lane];
        gh1 += x*whhT[k*192 + 64 + lane];
        gh2 += x*whhT[k*192 + 128 + lane];
    }
    float r  = sigmoidf_(gi0 + gh0);
    float z  = sigmoidf_(gi1 + gh1);
    float nn = tanhf_(gi2 + r*gh2);
    float hold = sm_h[w][lane];
    float hnew = (1.f - z)*nn + z*hold;
    h[n*HDIM + lane] = hnew;
    sm_t[w][lane] = hnew;               // sm_t free (readers done before last sync)
    __syncthreads();

    // decoder layer 1 (64 -> 64, relu)
    float d1 = de_b1[lane];
    #pragma unroll 4
    for (int k=0;k<HDIM;++k) d1 += sm_t[w][k]*dew1T[k*HDIM + lane];
    d1 = fmaxf(d1, 0.f);
    sm_din[w][lane] = d1;               // sm_din free (readers done before last sync)
    __syncthreads();

    if (lane < LDIM){
        float o = de_b2[lane];
        #pragma unroll
        for (int k=0;k<HDIM;++k) o += sm_din[w][k]*de_w2[lane*HDIM+k];
        float lb = softplusf_(o);
        float ln = lb * (1.f + temp_sens[0]*(fec - 1.f));
        lice[n*LDIM + lane] = ln;
        out_t[n*LDIM + lane] = ln;
    }
}

// ---------------- launcher ----------------

extern "C" void kernel_launch(void* const* d_in, const int* in_sizes, int n_in,
                              void* d_out, int out_size, void* d_ws, size_t ws_size,
                              hipStream_t stream) {
    const float* nfs       = (const float*)d_in[0];
    const float* init_lice = (const float*)d_in[1];
    const float* dist      = (const float*)d_in[2];
    const float* dirn      = (const float*)d_in[3];
    const float* ee_w1     = (const float*)d_in[4];
    const float* ee_b1     = (const float*)d_in[5];
    const float* ee_w2     = (const float*)d_in[6];
    const float* ee_b2     = (const float*)d_in[7];
    const float* at_w1     = (const float*)d_in[8];
    const float* at_b1     = (const float*)d_in[9];
    const float* at_w2     = (const float*)d_in[10];
    const float* at_b2     = (const float*)d_in[11];
    const float* en_w1     = (const float*)d_in[12];
    const float* en_b1     = (const float*)d_in[13];
    const float* en_w2     = (const float*)d_in[14];
    const float* en_b2     = (const float*)d_in[15];
    const float* fe_w1     = (const float*)d_in[16];
    const float* fe_b1     = (const float*)d_in[17];
    const float* fe_w2     = (const float*)d_in[18];
    const float* fe_b2     = (const float*)d_in[19];
    const float* fe_w3     = (const float*)d_in[20];
    const float* fe_b3     = (const float*)d_in[21];
    const float* gru_wih   = (const float*)d_in[22];
    const float* gru_whh   = (const float*)d_in[23];
    const float* gru_bih   = (const float*)d_in[24];
    const float* gru_bhh   = (const float*)d_in[25];
    const float* de_w1     = (const float*)d_in[26];
    const float* de_b1     = (const float*)d_in[27];
    const float* de_w2     = (const float*)d_in[28];
    const float* de_b2     = (const float*)d_in[29];
    const float* log_beta  = (const float*)d_in[30];
    const float* temp_sens = (const float*)d_in[31];
    const int*   ei        = (const int*)d_in[32];
    const int*   ei_src = ei;
    const int*   ei_dst = ei + NEDGES;
    float* out = (float*)d_out;

    // workspace carve (floats)
    float* wsf = (float*)d_ws;
    size_t off = 0;
    float* h        = wsf + off; off += (size_t)NNODES*HDIM;   // 640000
    float* lice     = wsf + off; off += (size_t)NNODES*LDIM;   // 30000
    float* logits   = wsf + off; off += (size_t)NEDGES;        // 320000
    float* pressure = wsf + off; off += (size_t)NNODES*HDIM;   // 640000
    float* Mmat     = wsf + off; off += 64*64;                 // 4096
    float* A2mat    = wsf + off; off += 64*64;                 // 4096
    float* cvec     = wsf + off; off += 64;
    float* wihT     = wsf + off; off += 72*192;                // 13824
    float* whhT     = wsf + off; off += 64*192;                // 12288
    float* enw2T    = wsf + off; off += 64*64;                 // 4096
    float* dew1T    = wsf + off; off += 64*64;                 // 4096
    int* counts = (int*)(wsf + off); off += NNODES;
    int* rowptr = (int*)(wsf + off); off += NNODES+1;
    int* cursor = (int*)(wsf + off); off += NNODES;
    int* perm   = (int*)(wsf + off); off += NEDGES;

    // setup
    k_init<<<2500,256,0,stream>>>(init_lice, gru_wih, gru_whh, en_w2, de_w1,
                                  h, lice, wihT, whhT, enw2T, dew1T, counts);
    k_prep<<<16,256,0,stream>>>(ee_w2, ee_b2, at_w1, at_b1, Mmat, A2mat, cvec);
    k_hist<<<1250,256,0,stream>>>(ei_dst, counts);
    k_scan<<<1,1024,0,stream>>>(counts, rowptr, cursor);
    k_scatter<<<1250,256,0,stream>>>(ei_dst, rowptr, cursor, perm);

    for (int t=0; t<T_STEPS; ++t){
        const float* xt = nfs + (size_t)t*NNODES*NFEAT;
        k_edge_logits<<<1250,256,0,stream>>>(xt, h, ei_src, dist, dirn,
                                             ee_w1, ee_b1,
                                             Mmat, A2mat, cvec,
                                             at_w2, at_b2, logits);
        k_softmax_pressure<<<2500,256,0,stream>>>(logits, h, lice, ei_src,
                                                  rowptr, perm, log_beta, pressure);
        k_node_update<<<2500,256,0,stream>>>(xt, h, lice, pressure,
                                             en_w1, en_b1, enw2T, en_b2,
                                             fe_w1, fe_b1, fe_w2, fe_b2, fe_w3, fe_b3,
                                             wihT, whhT, gru_bih, gru_bhh,
                                             dew1T, de_b1, de_w2, de_b2,
                                             temp_sens, out + (size_t)t*NNODES*LDIM);
    }
}

// Round 3
// 1113.817 us; speedup vs baseline: 2.1203x; 1.2202x over previous
//
#include <hip/hip_runtime.h>
#include <math.h>

#define T_STEPS 8
#define NNODES 10000
#define NFEAT 16
#define NEDGES 320000
#define HDIM 64
#define LDIM 3
#define CAP 128

__device__ __forceinline__ float sigmoidf_(float x){ return 1.f/(1.f+__expf(-x)); }
__device__ __forceinline__ float softplusf_(float x){ return fmaxf(x,0.f)+log1pf(__expf(-fabsf(x))); }
__device__ __forceinline__ float tanhf_(float x){ return 2.f*sigmoidf_(2.f*x)-1.f; }

// ---------------- setup kernels (once per call) ----------------

// Collapse ee-layer2 + attention-layer1(ef half): M[m][j] = sum_k ee_w2[k][m]*at_w1[j][k]
// cvec[j] = at_b1[j] + sum_k ee_b2[k]*at_w1[j][k];  A2[m][j] = at_w1[j][64+m]
__global__ void __launch_bounds__(256) k_prep(
    const float* __restrict__ ee_w2, const float* __restrict__ ee_b2,
    const float* __restrict__ at_w1, const float* __restrict__ at_b1,
    float* __restrict__ M, float* __restrict__ A2, float* __restrict__ cvec)
{
    int i = blockIdx.x*256 + threadIdx.x;   // 0..4095
    if (i >= 64*64) return;
    int m = i>>6, j = i&63;
    float acc = 0.f;
    #pragma unroll 8
    for (int k=0;k<64;++k) acc += ee_w2[k*64+m]*at_w1[j*128+k];
    M[i] = acc;
    A2[i] = at_w1[j*128+64+m];
    if (m == 0){
        float c = at_b1[j];
        #pragma unroll 8
        for (int k=0;k<64;++k) c += ee_b2[k]*at_w1[j*128+k];
        cvec[j] = c;
    }
}

__global__ void __launch_bounds__(256) k_init(
    const float* __restrict__ init_lice, const float* __restrict__ cvec,
    const float* __restrict__ gru_wih, const float* __restrict__ gru_whh,
    const float* __restrict__ en_w2, const float* __restrict__ de_w1,
    float* __restrict__ h, float* __restrict__ lice, float* __restrict__ G,
    float* __restrict__ wihT, float* __restrict__ whhT,
    float* __restrict__ enw2T, float* __restrict__ dew1T,
    int* __restrict__ counts)
{
    int i = blockIdx.x*256 + threadIdx.x;              // 0 .. 639999
    if (i < NNODES*HDIM){ h[i] = 0.f; G[i] = cvec[i&63]; }
    if (i < NNODES*LDIM) lice[i] = init_lice[i];
    if (i < NNODES) counts[i] = 0;
    if (i < 72*192){ int k = i/192, j = i%192; wihT[i] = gru_wih[j*72+k]; }       // (72,192)
    if (i < 64*192){ int k = i/192, j = i%192; whhT[i] = gru_whh[j*64+k]; }       // (64,192)
    if (i < 64*64){ int k = i>>6, j = i&63; enw2T[i] = en_w2[j*64+k]; }           // (64,64)
    if (i < 64*64){ int k = i>>6, j = i&63; dew1T[i] = de_w1[j*64+k]; }           // (64,64)
}

__global__ void __launch_bounds__(256) k_hist(const int* __restrict__ ei_dst, int* __restrict__ counts){
    int e = blockIdx.x*256 + threadIdx.x;
    if (e < NEDGES) atomicAdd(&counts[ei_dst[e]], 1);
}

__global__ void __launch_bounds__(1024) k_scan(const int* __restrict__ counts,
                                               int* __restrict__ rowptr, int* __restrict__ cursor){
    __shared__ int sums[1024];
    int t = threadIdx.x;
    const int CH = 10;                      // 1000 threads x 10 = 10000
    int c0 = t*CH;
    int s = 0;
    if (c0 < NNODES){
        #pragma unroll
        for (int i=0;i<CH;i++) s += counts[c0+i];
    }
    sums[t] = s;
    __syncthreads();
    for (int off=1; off<1024; off<<=1){
        int v = (t>=off) ? sums[t-off] : 0;
        __syncthreads();
        sums[t] += v;
        __syncthreads();
    }
    if (c0 < NNODES){
        int run = (t==0) ? 0 : sums[t-1];
        for (int i=0;i<CH;i++){ rowptr[c0+i] = run; run += counts[c0+i]; cursor[c0+i] = 0; }
        if (t == (NNODES/CH)-1) rowptr[NNODES] = run;
    }
}

__global__ void __launch_bounds__(256) k_scatter(const int* __restrict__ ei_dst,
        const int* __restrict__ rowptr, int* __restrict__ cursor, int* __restrict__ perm){
    int e = blockIdx.x*256 + threadIdx.x;
    if (e >= NEDGES) return;
    int d = ei_dst[e];
    int pos = rowptr[d] + atomicAdd(&cursor[d], 1);
    perm[pos] = e;
}

// ---------------- per-step kernel 1: edge MLPs -> logits ----------------
// ah[j] = G[src][j] + sum_m relu(h1_m)*M[m][j];  G = cvec + h @ A2 precomputed per node.

__global__ void __launch_bounds__(256,4) k_edge_logits(
    const float* __restrict__ xt, const float* __restrict__ G,
    const int* __restrict__ ei_src,
    const float* __restrict__ dist, const float* __restrict__ dirn,
    const float* __restrict__ ee_w1, const float* __restrict__ ee_b1,
    const float* __restrict__ M,
    const float* __restrict__ at_w2, const float* __restrict__ at_b2,
    float* __restrict__ logits)
{
    int e = blockIdx.x*256 + threadIdx.x;
    int src = ei_src[e];
    float d  = dist[e];
    float2 dir2 = *reinterpret_cast<const float2*>(dirn + 2*e);
    float temp = xt[src*NFEAT+11];
    float4 q  = *reinterpret_cast<const float4*>(xt + src*NFEAT + 12); // sal,u,v,pad
    float flux = q.y*dir2.x + q.z*dir2.y;
    float wflux = fmaxf(flux, 0.f) * __expf(-d*(1.f/15.f));
    float a0 = d, a1 = wflux, a2 = temp, a3 = q.x;

    float ah[HDIM];
    const float4* gs4 = reinterpret_cast<const float4*>(G + src*HDIM);
    #pragma unroll
    for (int jj=0;jj<16;++jj){
        float4 g = gs4[jj];
        ah[4*jj+0]=g.x; ah[4*jj+1]=g.y; ah[4*jj+2]=g.z; ah[4*jj+3]=g.w;
    }

    #pragma unroll 1
    for (int m=0;m<HDIM;++m){
        float4 w1 = *reinterpret_cast<const float4*>(ee_w1 + m*4);   // uniform -> s_load
        float h1m = fmaxf(ee_b1[m] + a0*w1.x + a1*w1.y + a2*w1.z + a3*w1.w, 0.f);
        #pragma unroll
        for (int j=0;j<HDIM;++j) ah[j] += h1m*M[m*HDIM+j];
    }
    float logit = at_b2[0];
    #pragma unroll
    for (int j=0;j<HDIM;++j) logit += at_w2[j]*fmaxf(ah[j], 0.f);

    logits[e] = logit + __logf(wflux + 1e-8f);
}

// ---------------- per-step kernel 2: segment softmax + pressure ----------------
// block-per-node (4 waves). Waves split edges 4-way; LDS reduce partial pressure.

__global__ void __launch_bounds__(256) k_softmax_pressure(
    const float* __restrict__ logits, const float* __restrict__ h,
    const float* __restrict__ lice, const int* __restrict__ ei_src,
    const int* __restrict__ rowptr, const int* __restrict__ perm,
    const float* __restrict__ log_beta,
    float* __restrict__ pressure)
{
    __shared__ float swgt[CAP];
    __shared__ int   ssrc[CAP];
    __shared__ float sred[4][64];
    __shared__ float sredm[4], sreds[4];

    const int node = blockIdx.x;
    const int tid = threadIdx.x;
    const int wid = tid >> 6;
    const int lane = tid & 63;
    const int start = rowptr[node], end = rowptr[node+1];
    const int deg = end - start;
    const int nfast = deg < CAP ? deg : CAP;

    // pass 1: cache logits/src in LDS, block max
    float m = -INFINITY;
    for (int i=start+tid; i<end; i+=256){
        int e = perm[i];
        float lg = logits[e];
        int o = i - start;
        if (o < CAP){ swgt[o] = lg; ssrc[o] = ei_src[e]; }
        m = fmaxf(m, lg);
    }
    #pragma unroll
    for (int off=32; off>=1; off>>=1) m = fmaxf(m, __shfl_xor(m, off));
    if (lane == 0) sredm[wid] = m;
    __syncthreads();
    m = fmaxf(fmaxf(sredm[0], sredm[1]), fmaxf(sredm[2], sredm[3]));

    // pass 2: block sum of exp
    float s = 0.f;
    for (int i=start+tid; i<end; i+=256){
        int o = i - start;
        float lg = (o < CAP) ? swgt[o] : logits[perm[i]];
        s += __expf(lg - m);
    }
    #pragma unroll
    for (int off=32; off>=1; off>>=1) s += __shfl_xor(s, off);
    if (lane == 0) sreds[wid] = s;
    __syncthreads();
    s = (sreds[0]+sreds[1])+(sreds[2]+sreds[3]);

    const float binv = __expf(log_beta[0])/(s + 1e-8f);

    // pass 3: cached logits -> final weights
    for (int o=tid; o<nfast; o+=256){
        int sc = ssrc[o];
        swgt[o] = __expf(swgt[o] - m) * binv * lice[sc*LDIM];
    }
    __syncthreads();

    // pass 4: waves split edges, lane = feature
    float p = 0.f;
    for (int o=wid; o<nfast; o+=4)
        p += swgt[o]*h[ssrc[o]*HDIM + lane];
    for (int i=start+CAP+wid; i<end; i+=4){      // rare tail (deg > CAP)
        int e = perm[i];
        int sc = ei_src[e];
        float wg = __expf(logits[e]-m)*binv*lice[sc*LDIM];
        p += wg*h[sc*HDIM+lane];
    }
    sred[wid][lane] = p;
    __syncthreads();
    if (wid == 0)
        pressure[node*HDIM + lane] = (sred[0][lane]+sred[1][lane])+(sred[2][lane]+sred[3][lane]);
}

// ---------------- per-step kernel 3: node update + G projection ----------------
// 512 threads = 8 waves = 8 nodes per block; big weights staged in LDS phase-by-phase.

#define NU_THREADS 512
#define NU_NODES 8

__global__ void __launch_bounds__(NU_THREADS) k_node_update(
    const float* __restrict__ xt,
    float* __restrict__ h, float* __restrict__ lice,
    const float* __restrict__ pressure,
    const float* __restrict__ en_w1, const float* __restrict__ en_b1,
    const float* __restrict__ enw2T, const float* __restrict__ en_b2,
    const float* __restrict__ fe_w1, const float* __restrict__ fe_b1,
    const float* __restrict__ fe_w2, const float* __restrict__ fe_b2,
    const float* __restrict__ fe_w3, const float* __restrict__ fe_b3,
    const float* __restrict__ wihT, const float* __restrict__ whhT,
    const float* __restrict__ gru_bih, const float* __restrict__ gru_bhh,
    const float* __restrict__ dew1T, const float* __restrict__ de_b1,
    const float* __restrict__ de_w2, const float* __restrict__ de_b2,
    const float* __restrict__ A2, const float* __restrict__ cvec,
    const float* __restrict__ temp_sens,
    float* __restrict__ G, float* __restrict__ out_t)
{
    const int tid = threadIdx.x;
    const int w = tid >> 6;
    const int lane = tid & 63;
    const int n = blockIdx.x*NU_NODES + w;

    __shared__ float wbuf[6912];            // 27 KB staging buffer
    __shared__ float s_din[NU_NODES][80];   // 72 used
    __shared__ float s_h[NU_NODES][64];
    __shared__ float s_t[NU_NODES][64];
    __shared__ float s_a[NU_NODES][32];

    auto stage = [&](const float* __restrict__ src, int nfloats){
        const float4* s4 = reinterpret_cast<const float4*>(src);
        float4* d4 = reinterpret_cast<float4*>(wbuf);
        int n4 = nfloats >> 2;
        for (int i=tid; i<n4; i+=NU_THREADS) d4[i] = s4[i];
    };

    // ---- phase 0: inputs, enc1, fec hidden (small weights via cache) ----
    const float* xr = xt + n*NFEAT;
    float env0 = xr[11], env1 = xr[12], env2 = xr[13], env3 = xr[14], env4 = xr[15];
    float tn = (env0 - 10.f)*(1.f/5.f);
    if (lane < 32) s_a[w][lane] = fmaxf(tn*fe_w1[lane] + fe_b1[lane], 0.f);
    float t1 = en_b1[lane] + env0*en_w1[lane*5+0] + env1*en_w1[lane*5+1]
             + env2*en_w1[lane*5+2] + env3*en_w1[lane*5+3] + env4*en_w1[lane*5+4];
    s_t[w][lane] = fmaxf(t1, 0.f);
    s_h[w][lane] = h[n*HDIM + lane];
    __syncthreads();                                    // s_a/s_t/s_h ready (wave-local anyway)

    // fec: 32->32 relu then 32->1, softplus
    float contrib = 0.f;
    if (lane < 32){
        float fb = fe_b2[lane];
        #pragma unroll
        for (int k=0;k<32;++k) fb += s_a[w][k]*fe_w2[lane*32+k];
        contrib = fmaxf(fb, 0.f)*fe_w3[lane];
    }
    #pragma unroll
    for (int off=32; off>=1; off>>=1) contrib += __shfl_xor(contrib, off);
    float fec = softplusf_(contrib + fe_b3[0]);

    // ---- phase 1: enc2 (stage enw2T 16KB) ----
    stage(enw2T, 64*64);
    __syncthreads();
    float enc = en_b2[lane];
    #pragma unroll 4
    for (int k=0;k<HDIM;++k) enc += s_t[w][k]*wbuf[k*64 + lane];
    s_din[w][lane] = enc + pressure[n*HDIM + lane];
    if (lane < 5) s_din[w][64+lane] = xr[11+lane];
    if (lane < 3) s_din[w][69+lane] = lice[n*LDIM + lane];
    __syncthreads();

    // ---- phase 2: GRU input side (wihT 72x192 in 2 chunks of 36 rows) ----
    float gi0 = gru_bih[lane], gi1 = gru_bih[64+lane], gi2 = gru_bih[128+lane];
    stage(wihT, 36*192);
    __syncthreads();
    #pragma unroll 4
    for (int k=0;k<36;++k){
        float x = s_din[w][k];
        gi0 += x*wbuf[k*192 + lane];
        gi1 += x*wbuf[k*192 + 64 + lane];
        gi2 += x*wbuf[k*192 + 128 + lane];
    }
    __syncthreads();
    stage(wihT + 36*192, 36*192);
    __syncthreads();
    #pragma unroll 4
    for (int k=0;k<36;++k){
        float x = s_din[w][36+k];
        gi0 += x*wbuf[k*192 + lane];
        gi1 += x*wbuf[k*192 + 64 + lane];
        gi2 += x*wbuf[k*192 + 128 + lane];
    }
    __syncthreads();

    // ---- phase 3: GRU hidden side (whhT 64x192 in 2 chunks of 32 rows) ----
    float gh0 = gru_bhh[lane], gh1 = gru_bhh[64+lane], gh2 = gru_bhh[128+lane];
    stage(whhT, 32*192);
    __syncthreads();
    #pragma unroll 4
    for (int k=0;k<32;++k){
        float x = s_h[w][k];
        gh0 += x*wbuf[k*192 + lane];
        gh1 += x*wbuf[k*192 + 64 + lane];
        gh2 += x*wbuf[k*192 + 128 + lane];
    }
    __syncthreads();
    stage(whhT + 32*192, 32*192);
    __syncthreads();
    #pragma unroll 4
    for (int k=0;k<32;++k){
        float x = s_h[w][32+k];
        gh0 += x*wbuf[k*192 + lane];
        gh1 += x*wbuf[k*192 + 64 + lane];
        gh2 += x*wbuf[k*192 + 128 + lane];
    }
    float r  = sigmoidf_(gi0 + gh0);
    float z  = sigmoidf_(gi1 + gh1);
    float nn = tanhf_(gi2 + r*gh2);
    float hnew = (1.f - z)*nn + z*s_h[w][lane];
    h[n*HDIM + lane] = hnew;
    __syncthreads();                        // all waves done with wbuf + s_h reads
    s_h[w][lane] = hnew;                    // wave-local overwrite

    // ---- phase 4: decoder layer 1 (dew1T 16KB) ----
    stage(dew1T, 64*64);
    __syncthreads();
    float d1 = de_b1[lane];
    #pragma unroll 4
    for (int k=0;k<HDIM;++k) d1 += s_h[w][k]*wbuf[k*64 + lane];
    s_t[w][lane] = fmaxf(d1, 0.f);
    __syncthreads();

    // ---- phase 5: G projection for next step (A2 16KB) ----
    stage(A2, 64*64);
    __syncthreads();
    float g = cvec[lane];
    #pragma unroll 4
    for (int k=0;k<HDIM;++k) g += s_h[w][k]*wbuf[k*64 + lane];
    G[n*HDIM + lane] = g;

    // ---- phase 6: decoder layer 2 + output (wave-local) ----
    if (lane < LDIM){
        float o = de_b2[lane];
        #pragma unroll
        for (int k=0;k<HDIM;++k) o += s_t[w][k]*de_w2[lane*HDIM+k];
        float lb = softplusf_(o);
        float ln = lb * (1.f + temp_sens[0]*(fec - 1.f));
        lice[n*LDIM + lane] = ln;
        out_t[n*LDIM + lane] = ln;
    }
}

// ---------------- launcher ----------------

extern "C" void kernel_launch(void* const* d_in, const int* in_sizes, int n_in,
                              void* d_out, int out_size, void* d_ws, size_t ws_size,
                              hipStream_t stream) {
    const float* nfs       = (const float*)d_in[0];
    const float* init_lice = (const float*)d_in[1];
    const float* dist      = (const float*)d_in[2];
    const float* dirn      = (const float*)d_in[3];
    const float* ee_w1     = (const float*)d_in[4];
    const float* ee_b1     = (const float*)d_in[5];
    const float* ee_w2     = (const float*)d_in[6];
    const float* ee_b2     = (const float*)d_in[7];
    const float* at_w1     = (const float*)d_in[8];
    const float* at_b1     = (const float*)d_in[9];
    const float* at_w2     = (const float*)d_in[10];
    const float* at_b2     = (const float*)d_in[11];
    const float* en_w1     = (const float*)d_in[12];
    const float* en_b1     = (const float*)d_in[13];
    const float* en_w2     = (const float*)d_in[14];
    const float* en_b2     = (const float*)d_in[15];
    const float* fe_w1     = (const float*)d_in[16];
    const float* fe_b1     = (const float*)d_in[17];
    const float* fe_w2     = (const float*)d_in[18];
    const float* fe_b2     = (const float*)d_in[19];
    const float* fe_w3     = (const float*)d_in[20];
    const float* fe_b3     = (const float*)d_in[21];
    const float* gru_wih   = (const float*)d_in[22];
    const float* gru_whh   = (const float*)d_in[23];
    const float* gru_bih   = (const float*)d_in[24];
    const float* gru_bhh   = (const float*)d_in[25];
    const float* de_w1     = (const float*)d_in[26];
    const float* de_b1     = (const float*)d_in[27];
    const float* de_w2     = (const float*)d_in[28];
    const float* de_b2     = (const float*)d_in[29];
    const float* log_beta  = (const float*)d_in[30];
    const float* temp_sens = (const float*)d_in[31];
    const int*   ei        = (const int*)d_in[32];
    const int*   ei_src = ei;
    const int*   ei_dst = ei + NEDGES;
    float* out = (float*)d_out;

    // workspace carve (floats; keep offsets %4 for float4 staging)
    float* wsf = (float*)d_ws;
    size_t off = 0;
    float* h        = wsf + off; off += (size_t)NNODES*HDIM;   // 640000
    float* lice     = wsf + off; off += (size_t)NNODES*LDIM;   // 30000
    float* logits   = wsf + off; off += (size_t)NEDGES;        // 320000
    float* pressure = wsf + off; off += (size_t)NNODES*HDIM;   // 640000
    float* G        = wsf + off; off += (size_t)NNODES*HDIM;   // 640000
    float* Mmat     = wsf + off; off += 64*64;                 // 4096
    float* A2mat    = wsf + off; off += 64*64;                 // 4096
    float* cvec     = wsf + off; off += 64;
    float* wihT     = wsf + off; off += 72*192;                // 13824
    float* whhT     = wsf + off; off += 64*192;                // 12288
    float* enw2T    = wsf + off; off += 64*64;                 // 4096
    float* dew1T    = wsf + off; off += 64*64;                 // 4096
    int* counts = (int*)(wsf + off); off += NNODES;
    int* rowptr = (int*)(wsf + off); off += NNODES+1;
    int* cursor = (int*)(wsf + off); off += NNODES;
    int* perm   = (int*)(wsf + off); off += NEDGES;

    // setup (k_prep first: k_init consumes cvec)
    k_prep<<<16,256,0,stream>>>(ee_w2, ee_b2, at_w1, at_b1, Mmat, A2mat, cvec);
    k_init<<<2500,256,0,stream>>>(init_lice, cvec, gru_wih, gru_whh, en_w2, de_w1,
                                  h, lice, G, wihT, whhT, enw2T, dew1T, counts);
    k_hist<<<1250,256,0,stream>>>(ei_dst, counts);
    k_scan<<<1,1024,0,stream>>>(counts, rowptr, cursor);
    k_scatter<<<1250,256,0,stream>>>(ei_dst, rowptr, cursor, perm);

    for (int t=0; t<T_STEPS; ++t){
        const float* xt = nfs + (size_t)t*NNODES*NFEAT;
        k_edge_logits<<<1250,256,0,stream>>>(xt, G, ei_src, dist, dirn,
                                             ee_w1, ee_b1, Mmat,
                                             at_w2, at_b2, logits);
        k_softmax_pressure<<<NNODES,256,0,stream>>>(logits, h, lice, ei_src,
                                                    rowptr, perm, log_beta, pressure);
        k_node_update<<<NNODES/NU_NODES,NU_THREADS,0,stream>>>(xt, h, lice, pressure,
                                             en_w1, en_b1, enw2T, en_b2,
                                             fe_w1, fe_b1, fe_w2, fe_b2, fe_w3, fe_b3,
                                             wihT, whhT, gru_bih, gru_bhh,
                                             dew1T, de_b1, de_w2, de_b2,
                                             A2mat, cvec, temp_sens,
                                             G, out + (size_t)t*NNODES*LDIM);
    }
}

// Round 4
// 1042.068 us; speedup vs baseline: 2.2663x; 1.0689x over previous
//
#include <hip/hip_runtime.h>
#include <math.h>

#define T_STEPS 8
#define NNODES 10000
#define NFEAT 16
#define NEDGES 320000
#define HDIM 64
#define LDIM 3
#define CAP 128

__device__ __forceinline__ float sigmoidf_(float x){ return 1.f/(1.f+__expf(-x)); }
__device__ __forceinline__ float softplusf_(float x){ return fmaxf(x,0.f)+log1pf(__expf(-fabsf(x))); }
__device__ __forceinline__ float tanhf_(float x){ return 2.f*sigmoidf_(2.f*x)-1.f; }

// ---------------- setup kernels (once per call) ----------------

// Collapse ee-layer2 + attention-layer1(ef half): M[m][j] = sum_k ee_w2[k][m]*at_w1[j][k]
// cvec[j] = at_b1[j] + sum_k ee_b2[k]*at_w1[j][k]
__global__ void __launch_bounds__(256) k_prep(
    const float* __restrict__ ee_w2, const float* __restrict__ ee_b2,
    const float* __restrict__ at_w1, const float* __restrict__ at_b1,
    float* __restrict__ M, float* __restrict__ cvec)
{
    int i = blockIdx.x*256 + threadIdx.x;   // 0..4095
    if (i >= 64*64) return;
    int m = i>>6, j = i&63;
    float acc = 0.f;
    #pragma unroll 8
    for (int k=0;k<64;++k) acc += ee_w2[k*64+m]*at_w1[j*128+k];
    M[i] = acc;
    if (m == 0){
        float c = at_b1[j];
        #pragma unroll 8
        for (int k=0;k<64;++k) c += ee_b2[k]*at_w1[j*128+k];
        cvec[j] = c;
    }
}

// init state + pack weights into k4-major float4 layouts for the node kernel
__global__ void __launch_bounds__(256) k_init(
    const float* __restrict__ init_lice, const float* __restrict__ cvec,
    const float* __restrict__ gru_wih, const float* __restrict__ gru_whh,
    const float* __restrict__ en_w2, const float* __restrict__ de_w1,
    const float* __restrict__ at_w1,
    float* __restrict__ h, float* __restrict__ lice, float* __restrict__ G,
    float* __restrict__ P_en, float* __restrict__ P_wih, float* __restrict__ P_whh,
    float* __restrict__ P_de, float* __restrict__ P_a2,
    int* __restrict__ counts)
{
    int i = blockIdx.x*256 + threadIdx.x;              // 0 .. 639999
    if (i < NNODES*HDIM){ h[i] = 0.f; G[i] = cvec[i&63]; }
    if (i < NNODES*LDIM) lice[i] = init_lice[i];
    if (i < NNODES) counts[i] = 0;
    if (i < 13824){                                   // P_wih[((k4*64+j)*3+g)*4+kk]
        int k4 = i/768, r = i%768, j = r/12, rr = r%12, g = rr>>2, kk = rr&3;
        P_wih[i] = gru_wih[(g*64+j)*72 + 4*k4 + kk];
    }
    if (i < 12288){                                   // P_whh
        int k4 = i/768, r = i%768, j = r/12, rr = r%12, g = rr>>2, kk = rr&3;
        P_whh[i] = gru_whh[(g*64+j)*64 + 4*k4 + kk];
    }
    if (i < 4096){                                    // P_en[(k4*64+j)*4+kk]
        int k4 = i>>8, r = i&255, j = r>>2, kk = r&3;
        P_en[i] = en_w2[j*64 + 4*k4 + kk];
        P_de[i] = de_w1[j*64 + 4*k4 + kk];
        P_a2[i] = at_w1[j*128 + 64 + 4*k4 + kk];
    }
}

// fec depends only on temp -> precompute for all (t,n)
__global__ void __launch_bounds__(256) k_fec(
    const float* __restrict__ nfs,
    const float* __restrict__ fe_w1, const float* __restrict__ fe_b1,
    const float* __restrict__ fe_w2, const float* __restrict__ fe_b2,
    const float* __restrict__ fe_w3, const float* __restrict__ fe_b3,
    float* __restrict__ fec_arr)
{
    int i = blockIdx.x*256 + threadIdx.x;
    if (i >= T_STEPS*NNODES) return;
    float temp = nfs[(size_t)i*NFEAT + 11];
    float tn = (temp - 10.f)*(1.f/5.f);
    float a[32];
    #pragma unroll
    for (int k=0;k<32;++k) a[k] = fmaxf(tn*fe_w1[k] + fe_b1[k], 0.f);
    float o = fe_b3[0];
    #pragma unroll 4
    for (int l=0;l<32;++l){
        float b = fe_b2[l];
        #pragma unroll
        for (int k=0;k<32;++k) b += a[k]*fe_w2[l*32+k];
        o += fmaxf(b, 0.f)*fe_w3[l];
    }
    fec_arr[i] = softplusf_(o);
}

__global__ void __launch_bounds__(256) k_hist(const int* __restrict__ ei_dst, int* __restrict__ counts){
    int e = blockIdx.x*256 + threadIdx.x;
    if (e < NEDGES) atomicAdd(&counts[ei_dst[e]], 1);
}

__global__ void __launch_bounds__(1024) k_scan(const int* __restrict__ counts,
                                               int* __restrict__ rowptr, int* __restrict__ cursor){
    __shared__ int sums[1024];
    int t = threadIdx.x;
    const int CH = 10;
    int c0 = t*CH;
    int s = 0;
    if (c0 < NNODES){
        #pragma unroll
        for (int i=0;i<CH;i++) s += counts[c0+i];
    }
    sums[t] = s;
    __syncthreads();
    for (int off=1; off<1024; off<<=1){
        int v = (t>=off) ? sums[t-off] : 0;
        __syncthreads();
        sums[t] += v;
        __syncthreads();
    }
    if (c0 < NNODES){
        int run = (t==0) ? 0 : sums[t-1];
        for (int i=0;i<CH;i++){ rowptr[c0+i] = run; run += counts[c0+i]; cursor[c0+i] = 0; }
        if (t == (NNODES/CH)-1) rowptr[NNODES] = run;
    }
}

__global__ void __launch_bounds__(256) k_scatter(const int* __restrict__ ei_dst,
        const int* __restrict__ rowptr, int* __restrict__ cursor, int* __restrict__ perm){
    int e = blockIdx.x*256 + threadIdx.x;
    if (e >= NEDGES) return;
    int d = ei_dst[e];
    int pos = rowptr[d] + atomicAdd(&cursor[d], 1);
    perm[pos] = e;
}

// ---------------- per-step kernel 1: edge MLPs -> logits ----------------

__global__ void __launch_bounds__(256,4) k_edge_logits(
    const float* __restrict__ xt, const float* __restrict__ G,
    const int* __restrict__ ei_src,
    const float* __restrict__ dist, const float* __restrict__ dirn,
    const float* __restrict__ ee_w1, const float* __restrict__ ee_b1,
    const float* __restrict__ M,
    const float* __restrict__ at_w2, const float* __restrict__ at_b2,
    float* __restrict__ logits)
{
    int e = blockIdx.x*256 + threadIdx.x;
    int src = ei_src[e];
    float d  = dist[e];
    float2 dir2 = *reinterpret_cast<const float2*>(dirn + 2*e);
    float temp = xt[src*NFEAT+11];
    float4 q  = *reinterpret_cast<const float4*>(xt + src*NFEAT + 12); // sal,u,v,pad
    float flux = q.y*dir2.x + q.z*dir2.y;
    float wflux = fmaxf(flux, 0.f) * __expf(-d*(1.f/15.f));
    float a0 = d, a1 = wflux, a2 = temp, a3 = q.x;

    float ah[HDIM];
    const float4* gs4 = reinterpret_cast<const float4*>(G + src*HDIM);
    #pragma unroll
    for (int jj=0;jj<16;++jj){
        float4 g = gs4[jj];
        ah[4*jj+0]=g.x; ah[4*jj+1]=g.y; ah[4*jj+2]=g.z; ah[4*jj+3]=g.w;
    }

    #pragma unroll 1
    for (int m=0;m<HDIM;++m){
        float4 w1 = *reinterpret_cast<const float4*>(ee_w1 + m*4);   // uniform -> s_load
        float h1m = fmaxf(ee_b1[m] + a0*w1.x + a1*w1.y + a2*w1.z + a3*w1.w, 0.f);
        #pragma unroll
        for (int j=0;j<HDIM;++j) ah[j] += h1m*M[m*HDIM+j];
    }
    float logit = at_b2[0];
    #pragma unroll
    for (int j=0;j<HDIM;++j) logit += at_w2[j]*fmaxf(ah[j], 0.f);

    logits[e] = logit + __logf(wflux + 1e-8f);
}

// ---------------- per-step kernel 2: segment softmax + pressure ----------------

__global__ void __launch_bounds__(256) k_softmax_pressure(
    const float* __restrict__ logits, const float* __restrict__ h,
    const float* __restrict__ lice, const int* __restrict__ ei_src,
    const int* __restrict__ rowptr, const int* __restrict__ perm,
    const float* __restrict__ log_beta,
    float* __restrict__ pressure)
{
    __shared__ float swgt[CAP];
    __shared__ int   ssrc[CAP];
    __shared__ float sred[4][64];
    __shared__ float sredm[4], sreds[4];

    const int node = blockIdx.x;
    const int tid = threadIdx.x;
    const int wid = tid >> 6;
    const int lane = tid & 63;
    const int start = rowptr[node], end = rowptr[node+1];
    const int deg = end - start;
    const int nfast = deg < CAP ? deg : CAP;

    float m = -INFINITY;
    for (int i=start+tid; i<end; i+=256){
        int e = perm[i];
        float lg = logits[e];
        int o = i - start;
        if (o < CAP){ swgt[o] = lg; ssrc[o] = ei_src[e]; }
        m = fmaxf(m, lg);
    }
    #pragma unroll
    for (int off=32; off>=1; off>>=1) m = fmaxf(m, __shfl_xor(m, off));
    if (lane == 0) sredm[wid] = m;
    __syncthreads();
    m = fmaxf(fmaxf(sredm[0], sredm[1]), fmaxf(sredm[2], sredm[3]));

    float s = 0.f;
    for (int i=start+tid; i<end; i+=256){
        int o = i - start;
        float lg = (o < CAP) ? swgt[o] : logits[perm[i]];
        s += __expf(lg - m);
    }
    #pragma unroll
    for (int off=32; off>=1; off>>=1) s += __shfl_xor(s, off);
    if (lane == 0) sreds[wid] = s;
    __syncthreads();
    s = (sreds[0]+sreds[1])+(sreds[2]+sreds[3]);

    const float binv = __expf(log_beta[0])/(s + 1e-8f);

    for (int o=tid; o<nfast; o+=256){
        int sc = ssrc[o];
        swgt[o] = __expf(swgt[o] - m) * binv * lice[sc*LDIM];
    }
    __syncthreads();

    float p = 0.f;
    for (int o=wid; o<nfast; o+=4)
        p += swgt[o]*h[ssrc[o]*HDIM + lane];
    for (int i=start+CAP+wid; i<end; i+=4){
        int e = perm[i];
        int sc = ei_src[e];
        float wg = __expf(logits[e]-m)*binv*lice[sc*LDIM];
        p += wg*h[sc*HDIM+lane];
    }
    sred[wid][lane] = p;
    __syncthreads();
    if (wid == 0)
        pressure[node*HDIM + lane] = (sred[0][lane]+sred[1][lane])+(sred[2][lane]+sred[3][lane]);
}

// ---------------- per-step kernel 3: node update + G projection ----------------
// 256 threads = 4 waves; 16 nodes/block, 4 nodes per wave (register-blocked).
// Weights staged phase-by-phase in wbuf as k4-major float4; inputs broadcast b128.

#define NU2_THREADS 256
#define NU2_NPB 16

__global__ void __launch_bounds__(NU2_THREADS) k_node_update(
    const float* __restrict__ xt,
    float* __restrict__ h, float* __restrict__ lice,
    const float* __restrict__ pressure,
    const float* __restrict__ en_w1, const float* __restrict__ en_b1, const float* __restrict__ en_b2,
    const float* __restrict__ P_en, const float* __restrict__ P_wih, const float* __restrict__ P_whh,
    const float* __restrict__ P_de, const float* __restrict__ P_a2,
    const float* __restrict__ gru_bih, const float* __restrict__ gru_bhh,
    const float* __restrict__ de_b1, const float* __restrict__ de_w2, const float* __restrict__ de_b2,
    const float* __restrict__ cvec, const float* __restrict__ fec_t,
    const float* __restrict__ temp_sens,
    float* __restrict__ G, float* __restrict__ out_t)
{
    __shared__ float wbuf[8192];             // 32 KB phase-staged weights
    __shared__ float s_din[NU2_NPB][76];     // din (72 used), float4-aligned rows
    __shared__ float s_h[NU2_NPB][64];       // h, then hnew (in-place, wave-local)
    __shared__ float s_x[NU2_NPB][64];       // enc1 output t1

    const int tid = threadIdx.x;
    const int wv = tid>>6, lane = tid&63;
    const int nb = blockIdx.x*NU2_NPB;

    auto stage4 = [&](const float* __restrict__ src, int nfl, int dstoff){
        const float4* s4 = reinterpret_cast<const float4*>(src);
        float4* d4 = reinterpret_cast<float4*>(wbuf + dstoff);
        for (int i=tid; i<(nfl>>2); i+=NU2_THREADS) d4[i] = s4[i];
    };

    // ---- phase 0: gather per-node state (wave-local LDS, no barrier needed) ----
    float hv[4], pm[4];
    #pragma unroll
    for (int m=0;m<4;++m){
        const int idx = wv*4+m, n = nb+idx;
        hv[m] = h[n*HDIM+lane];
        s_h[idx][lane] = hv[m];
        pm[m] = pressure[n*HDIM+lane];
        if (lane < 5)      s_din[idx][64+lane] = xt[n*NFEAT+11+lane];
        else if (lane < 8) s_din[idx][64+lane] = lice[n*LDIM + (lane-5)];
    }

    // ---- stage A: P_en + en_w1 ----
    stage4(P_en, 4096, 0);
    stage4(en_w1, 320, 4096);
    __syncthreads();

    // enc1 (5->64, relu)
    #pragma unroll
    for (int m=0;m<4;++m){
        const int idx = wv*4+m;
        float t1 = en_b1[lane];
        #pragma unroll
        for (int k=0;k<5;++k) t1 += s_din[idx][64+k]*wbuf[4096 + lane*5 + k];
        s_x[idx][lane] = fmaxf(t1, 0.f);
    }
    // enc2 (64->64) + pressure -> din
    float dinl[4];
    #pragma unroll
    for (int m=0;m<4;++m) dinl[m] = en_b2[lane] + pm[m];
    #pragma unroll 4
    for (int k4=0;k4<16;++k4){
        float4 w4 = *reinterpret_cast<const float4*>(&wbuf[(k4*64+lane)*4]);
        #pragma unroll
        for (int m=0;m<4;++m){
            float4 x4 = *reinterpret_cast<const float4*>(&s_x[wv*4+m][k4*4]);
            dinl[m] += x4.x*w4.x + x4.y*w4.y + x4.z*w4.z + x4.w*w4.w;
        }
    }
    #pragma unroll
    for (int m=0;m<4;++m) s_din[wv*4+m][lane] = dinl[m];
    __syncthreads();

    // ---- GRU input side: P_wih (18 k4) in 2 chunks of 9 ----
    float gi0[4], gi1[4], gi2[4];
    #pragma unroll
    for (int m=0;m<4;++m){
        gi0[m]=gru_bih[lane]; gi1[m]=gru_bih[64+lane]; gi2[m]=gru_bih[128+lane];
    }
    stage4(P_wih, 6912, 0);
    __syncthreads();
    #pragma unroll 3
    for (int k4=0;k4<9;++k4){
        const float* wp = &wbuf[(k4*64+lane)*12];
        float4 w0=*reinterpret_cast<const float4*>(wp);
        float4 w1=*reinterpret_cast<const float4*>(wp+4);
        float4 w2=*reinterpret_cast<const float4*>(wp+8);
        #pragma unroll
        for (int m=0;m<4;++m){
            float4 x4 = *reinterpret_cast<const float4*>(&s_din[wv*4+m][k4*4]);
            gi0[m] += x4.x*w0.x + x4.y*w0.y + x4.z*w0.z + x4.w*w0.w;
            gi1[m] += x4.x*w1.x + x4.y*w1.y + x4.z*w1.z + x4.w*w1.w;
            gi2[m] += x4.x*w2.x + x4.y*w2.y + x4.z*w2.z + x4.w*w2.w;
        }
    }
    __syncthreads();
    stage4(P_wih + 6912, 6912, 0);
    __syncthreads();
    #pragma unroll 3
    for (int k4=9;k4<18;++k4){
        const float* wp = &wbuf[((k4-9)*64+lane)*12];
        float4 w0=*reinterpret_cast<const float4*>(wp);
        float4 w1=*reinterpret_cast<const float4*>(wp+4);
        float4 w2=*reinterpret_cast<const float4*>(wp+8);
        #pragma unroll
        for (int m=0;m<4;++m){
            float4 x4 = *reinterpret_cast<const float4*>(&s_din[wv*4+m][k4*4]);
            gi0[m] += x4.x*w0.x + x4.y*w0.y + x4.z*w0.z + x4.w*w0.w;
            gi1[m] += x4.x*w1.x + x4.y*w1.y + x4.z*w1.z + x4.w*w1.w;
            gi2[m] += x4.x*w2.x + x4.y*w2.y + x4.z*w2.z + x4.w*w2.w;
        }
    }
    __syncthreads();

    // ---- GRU hidden side: P_whh (16 k4) in 2 chunks of 8 ----
    float gh0[4], gh1[4], gh2[4];
    #pragma unroll
    for (int m=0;m<4;++m){
        gh0[m]=gru_bhh[lane]; gh1[m]=gru_bhh[64+lane]; gh2[m]=gru_bhh[128+lane];
    }
    stage4(P_whh, 6144, 0);
    __syncthreads();
    #pragma unroll 3
    for (int k4=0;k4<8;++k4){
        const float* wp = &wbuf[(k4*64+lane)*12];
        float4 w0=*reinterpret_cast<const float4*>(wp);
        float4 w1=*reinterpret_cast<const float4*>(wp+4);
        float4 w2=*reinterpret_cast<const float4*>(wp+8);
        #pragma unroll
        for (int m=0;m<4;++m){
            float4 x4 = *reinterpret_cast<const float4*>(&s_h[wv*4+m][k4*4]);
            gh0[m] += x4.x*w0.x + x4.y*w0.y + x4.z*w0.z + x4.w*w0.w;
            gh1[m] += x4.x*w1.x + x4.y*w1.y + x4.z*w1.z + x4.w*w1.w;
            gh2[m] += x4.x*w2.x + x4.y*w2.y + x4.z*w2.z + x4.w*w2.w;
        }
    }
    __syncthreads();
    stage4(P_whh + 6144, 6144, 0);
    __syncthreads();
    #pragma unroll 3
    for (int k4=8;k4<16;++k4){
        const float* wp = &wbuf[((k4-8)*64+lane)*12];
        float4 w0=*reinterpret_cast<const float4*>(wp);
        float4 w1=*reinterpret_cast<const float4*>(wp+4);
        float4 w2=*reinterpret_cast<const float4*>(wp+8);
        #pragma unroll
        for (int m=0;m<4;++m){
            float4 x4 = *reinterpret_cast<const float4*>(&s_h[wv*4+m][k4*4]);
            gh0[m] += x4.x*w0.x + x4.y*w0.y + x4.z*w0.z + x4.w*w0.w;
            gh1[m] += x4.x*w1.x + x4.y*w1.y + x4.z*w1.z + x4.w*w1.w;
            gh2[m] += x4.x*w2.x + x4.y*w2.y + x4.z*w2.z + x4.w*w2.w;
        }
    }

    // ---- GRU glue (per-lane j); write hnew (global + in-place s_h, wave-local) ----
    #pragma unroll
    for (int m=0;m<4;++m){
        const int idx = wv*4+m, n = nb+idx;
        float r  = sigmoidf_(gi0[m] + gh0[m]);
        float z  = sigmoidf_(gi1[m] + gh1[m]);
        float nn = tanhf_(gi2[m] + r*gh2[m]);
        float hnew = (1.f - z)*nn + z*hv[m];
        h[n*HDIM+lane] = hnew;
        s_h[idx][lane] = hnew;
    }
    __syncthreads();

    // ---- stage D: P_de + P_a2 ----
    stage4(P_de, 4096, 0);
    stage4(P_a2, 4096, 4096);
    __syncthreads();

    // dec1 (64->64 relu) and G projection (cvec + hnew @ A2)
    float d1m[4], gv[4];
    #pragma unroll
    for (int m=0;m<4;++m){ d1m[m] = de_b1[lane]; gv[m] = cvec[lane]; }
    #pragma unroll 4
    for (int k4=0;k4<16;++k4){
        float4 wd = *reinterpret_cast<const float4*>(&wbuf[(k4*64+lane)*4]);
        float4 wa = *reinterpret_cast<const float4*>(&wbuf[4096 + (k4*64+lane)*4]);
        #pragma unroll
        for (int m=0;m<4;++m){
            float4 x4 = *reinterpret_cast<const float4*>(&s_h[wv*4+m][k4*4]);
            d1m[m] += x4.x*wd.x + x4.y*wd.y + x4.z*wd.z + x4.w*wd.w;
            gv[m]  += x4.x*wa.x + x4.y*wa.y + x4.z*wa.z + x4.w*wa.w;
        }
    }
    #pragma unroll
    for (int m=0;m<4;++m){
        const int n = nb+wv*4+m;
        G[n*HDIM+lane] = gv[m];
        d1m[m] = fmaxf(d1m[m], 0.f);
    }

    // dec2 (64->3) via shuffle reduce, then output
    #pragma unroll
    for (int m=0;m<4;++m){
        const int n = nb+wv*4+m;
        float s0 = d1m[m]*de_w2[lane];
        float s1 = d1m[m]*de_w2[64+lane];
        float s2 = d1m[m]*de_w2[128+lane];
        #pragma unroll
        for (int off=32; off>=1; off>>=1){
            s0 += __shfl_xor(s0, off);
            s1 += __shfl_xor(s1, off);
            s2 += __shfl_xor(s2, off);
        }
        float fec = fec_t[n];
        if (lane < LDIM){
            float oi = (lane==0 ? s0 : (lane==1 ? s1 : s2)) + de_b2[lane];
            float lb = softplusf_(oi);
            float ln = lb * (1.f + temp_sens[0]*(fec - 1.f));
            lice[n*LDIM+lane] = ln;
            out_t[n*LDIM+lane] = ln;
        }
    }
}

// ---------------- launcher ----------------

extern "C" void kernel_launch(void* const* d_in, const int* in_sizes, int n_in,
                              void* d_out, int out_size, void* d_ws, size_t ws_size,
                              hipStream_t stream) {
    const float* nfs       = (const float*)d_in[0];
    const float* init_lice = (const float*)d_in[1];
    const float* dist      = (const float*)d_in[2];
    const float* dirn      = (const float*)d_in[3];
    const float* ee_w1     = (const float*)d_in[4];
    const float* ee_b1     = (const float*)d_in[5];
    const float* ee_w2     = (const float*)d_in[6];
    const float* ee_b2     = (const float*)d_in[7];
    const float* at_w1     = (const float*)d_in[8];
    const float* at_b1     = (const float*)d_in[9];
    const float* at_w2     = (const float*)d_in[10];
    const float* at_b2     = (const float*)d_in[11];
    const float* en_w1     = (const float*)d_in[12];
    const float* en_b1     = (const float*)d_in[13];
    const float* en_w2     = (const float*)d_in[14];
    const float* en_b2     = (const float*)d_in[15];
    const float* fe_w1     = (const float*)d_in[16];
    const float* fe_b1     = (const float*)d_in[17];
    const float* fe_w2     = (const float*)d_in[18];
    const float* fe_b2     = (const float*)d_in[19];
    const float* fe_w3     = (const float*)d_in[20];
    const float* fe_b3     = (const float*)d_in[21];
    const float* gru_wih   = (const float*)d_in[22];
    const float* gru_whh   = (const float*)d_in[23];
    const float* gru_bih   = (const float*)d_in[24];
    const float* gru_bhh   = (const float*)d_in[25];
    const float* de_w1     = (const float*)d_in[26];
    const float* de_b1     = (const float*)d_in[27];
    const float* de_w2     = (const float*)d_in[28];
    const float* de_b2     = (const float*)d_in[29];
    const float* log_beta  = (const float*)d_in[30];
    const float* temp_sens = (const float*)d_in[31];
    const int*   ei        = (const int*)d_in[32];
    const int*   ei_src = ei;
    const int*   ei_dst = ei + NEDGES;
    float* out = (float*)d_out;

    // workspace carve (floats; keep offsets %4 for float4 staging)
    float* wsf = (float*)d_ws;
    size_t off = 0;
    float* h        = wsf + off; off += (size_t)NNODES*HDIM;   // 640000
    float* lice     = wsf + off; off += (size_t)NNODES*LDIM + 2; // 30002 -> keep %4
    off = (off + 3) & ~(size_t)3;
    float* logits   = wsf + off; off += (size_t)NEDGES;        // 320000
    float* pressure = wsf + off; off += (size_t)NNODES*HDIM;   // 640000
    float* G        = wsf + off; off += (size_t)NNODES*HDIM;   // 640000
    float* Mmat     = wsf + off; off += 64*64;
    float* cvec     = wsf + off; off += 64;
    float* P_en     = wsf + off; off += 4096;
    float* P_wih    = wsf + off; off += 13824;
    float* P_whh    = wsf + off; off += 12288;
    float* P_de     = wsf + off; off += 4096;
    float* P_a2     = wsf + off; off += 4096;
    float* fec_arr  = wsf + off; off += (size_t)T_STEPS*NNODES; // 80000
    int* counts = (int*)(wsf + off); off += NNODES;
    int* rowptr = (int*)(wsf + off); off += NNODES+1;
    int* cursor = (int*)(wsf + off); off += NNODES;
    int* perm   = (int*)(wsf + off); off += NEDGES;

    // setup (k_prep first: k_init consumes cvec)
    k_prep<<<16,256,0,stream>>>(ee_w2, ee_b2, at_w1, at_b1, Mmat, cvec);
    k_init<<<2500,256,0,stream>>>(init_lice, cvec, gru_wih, gru_whh, en_w2, de_w1, at_w1,
                                  h, lice, G, P_en, P_wih, P_whh, P_de, P_a2, counts);
    k_fec<<<(T_STEPS*NNODES+255)/256,256,0,stream>>>(nfs, fe_w1, fe_b1, fe_w2, fe_b2,
                                                     fe_w3, fe_b3, fec_arr);
    k_hist<<<1250,256,0,stream>>>(ei_dst, counts);
    k_scan<<<1,1024,0,stream>>>(counts, rowptr, cursor);
    k_scatter<<<1250,256,0,stream>>>(ei_dst, rowptr, cursor, perm);

    for (int t=0; t<T_STEPS; ++t){
        const float* xt = nfs + (size_t)t*NNODES*NFEAT;
        k_edge_logits<<<1250,256,0,stream>>>(xt, G, ei_src, dist, dirn,
                                             ee_w1, ee_b1, Mmat,
                                             at_w2, at_b2, logits);
        k_softmax_pressure<<<NNODES,256,0,stream>>>(logits, h, lice, ei_src,
                                                    rowptr, perm, log_beta, pressure);
        k_node_update<<<NNODES/NU2_NPB,NU2_THREADS,0,stream>>>(xt, h, lice, pressure,
                                             en_w1, en_b1, en_b2,
                                             P_en, P_wih, P_whh, P_de, P_a2,
                                             gru_bih, gru_bhh,
                                             de_b1, de_w2, de_b2,
                                             cvec, fec_arr + (size_t)t*NNODES,
                                             temp_sens,
                                             G, out + (size_t)t*NNODES*LDIM);
    }
}

// Round 6
// 957.470 us; speedup vs baseline: 2.4666x; 1.0884x over previous
//
#include <hip/hip_runtime.h>
#include <math.h>

#define T_STEPS 8
#define NNODES 10000
#define NFEAT 16
#define NEDGES 320000
#define HDIM 64
#define LDIM 3
#define CAP 128

typedef _Float16 f16x8 __attribute__((ext_vector_type(8)));
typedef float f32x4 __attribute__((ext_vector_type(4)));

__device__ __forceinline__ float sigmoidf_(float x){ return 1.f/(1.f+__expf(-x)); }
__device__ __forceinline__ float softplusf_(float x){ return fmaxf(x,0.f)+log1pf(__expf(-fabsf(x))); }
__device__ __forceinline__ float tanhf_(float x){ return 2.f*sigmoidf_(2.f*x)-1.f; }

// ---------------- setup kernels (once per call) ----------------

// Collapse ee-layer2 + attention-layer1(ef half): M[m][j] = sum_k ee_w2[k][m]*at_w1[j][k]
// Emit M as fp16 hi/lo MFMA B-fragments (16x16x32): frag (jt,ks), lane holds
// B[k][j] with j = jt*16+(lane&15), k = ks*32+(lane>>4)*8+elem.
// cvec[j] = at_b1[j] + sum_k ee_b2[k]*at_w1[j][k]
__global__ void __launch_bounds__(256) k_prep(
    const float* __restrict__ ee_w2, const float* __restrict__ ee_b2,
    const float* __restrict__ at_w1, const float* __restrict__ at_b1,
    _Float16* __restrict__ P_Mhi, _Float16* __restrict__ P_Mlo,
    float* __restrict__ cvec)
{
    int i = blockIdx.x*256 + threadIdx.x;   // 0..4095
    if (i >= 64*64) return;
    int m = i>>6, j = i&63;                 // m = K index, j = output col
    float acc = 0.f;
    #pragma unroll 8
    for (int k=0;k<64;++k) acc += ee_w2[k*64+m]*at_w1[j*128+k];
    int ks = m>>5;
    int lane = ((m>>3)&3)*16 + (j&15);
    int elem = m&7;
    int fi = (j>>4)*2 + ks;
    _Float16 hi = (_Float16)acc;
    P_Mhi[(fi*64+lane)*8+elem] = hi;
    P_Mlo[(fi*64+lane)*8+elem] = (_Float16)(acc - (float)hi);
    if (m == 0){
        float c = at_b1[j];
        #pragma unroll 8
        for (int k=0;k<64;++k) c += ee_b2[k]*at_w1[j*128+k];
        cvec[j] = c;
    }
}

// init state + pack weights into k4-major float4 layouts for the node kernel
__global__ void __launch_bounds__(256) k_init(
    const float* __restrict__ init_lice, const float* __restrict__ cvec,
    const float* __restrict__ gru_wih, const float* __restrict__ gru_whh,
    const float* __restrict__ en_w2, const float* __restrict__ de_w1,
    const float* __restrict__ at_w1,
    float* __restrict__ h, float* __restrict__ lice, float* __restrict__ G,
    float* __restrict__ P_en, float* __restrict__ P_wih, float* __restrict__ P_whh,
    float* __restrict__ P_de, float* __restrict__ P_a2,
    int* __restrict__ counts)
{
    int i = blockIdx.x*256 + threadIdx.x;              // 0 .. 639999
    if (i < NNODES*HDIM){ h[i] = 0.f; G[i] = cvec[i&63]; }
    if (i < NNODES*LDIM) lice[i] = init_lice[i];
    if (i < NNODES) counts[i] = 0;
    if (i < 13824){                                   // P_wih[((k4*64+j)*3+g)*4+kk]
        int k4 = i/768, r = i%768, j = r/12, rr = r%12, g = rr>>2, kk = rr&3;
        P_wih[i] = gru_wih[(g*64+j)*72 + 4*k4 + kk];
    }
    if (i < 12288){                                   // P_whh
        int k4 = i/768, r = i%768, j = r/12, rr = r%12, g = rr>>2, kk = rr&3;
        P_whh[i] = gru_whh[(g*64+j)*64 + 4*k4 + kk];
    }
    if (i < 4096){                                    // P_en[(k4*64+j)*4+kk]
        int k4 = i>>8, r = i&255, j = r>>2, kk = r&3;
        P_en[i] = en_w2[j*64 + 4*k4 + kk];
        P_de[i] = de_w1[j*64 + 4*k4 + kk];
        P_a2[i] = at_w1[j*128 + 64 + 4*k4 + kk];
    }
}

// fec depends only on temp -> precompute for all (t,n)
__global__ void __launch_bounds__(256) k_fec(
    const float* __restrict__ nfs,
    const float* __restrict__ fe_w1, const float* __restrict__ fe_b1,
    const float* __restrict__ fe_w2, const float* __restrict__ fe_b2,
    const float* __restrict__ fe_w3, const float* __restrict__ fe_b3,
    float* __restrict__ fec_arr)
{
    int i = blockIdx.x*256 + threadIdx.x;
    if (i >= T_STEPS*NNODES) return;
    float temp = nfs[(size_t)i*NFEAT + 11];
    float tn = (temp - 10.f)*(1.f/5.f);
    float a[32];
    #pragma unroll
    for (int k=0;k<32;++k) a[k] = fmaxf(tn*fe_w1[k] + fe_b1[k], 0.f);
    float o = fe_b3[0];
    #pragma unroll 4
    for (int l=0;l<32;++l){
        float b = fe_b2[l];
        #pragma unroll
        for (int k=0;k<32;++k) b += a[k]*fe_w2[l*32+k];
        o += fmaxf(b, 0.f)*fe_w3[l];
    }
    fec_arr[i] = softplusf_(o);
}

__global__ void __launch_bounds__(256) k_hist(const int* __restrict__ ei_dst, int* __restrict__ counts){
    int e = blockIdx.x*256 + threadIdx.x;
    if (e < NEDGES) atomicAdd(&counts[ei_dst[e]], 1);
}

__global__ void __launch_bounds__(1024) k_scan(const int* __restrict__ counts,
                                               int* __restrict__ rowptr, int* __restrict__ cursor){
    __shared__ int sums[1024];
    int t = threadIdx.x;
    const int CH = 10;
    int c0 = t*CH;
    int s = 0;
    if (c0 < NNODES){
        #pragma unroll
        for (int i=0;i<CH;i++) s += counts[c0+i];
    }
    sums[t] = s;
    __syncthreads();
    for (int off=1; off<1024; off<<=1){
        int v = (t>=off) ? sums[t-off] : 0;
        __syncthreads();
        sums[t] += v;
        __syncthreads();
    }
    if (c0 < NNODES){
        int run = (t==0) ? 0 : sums[t-1];
        for (int i=0;i<CH;i++){ rowptr[c0+i] = run; run += counts[c0+i]; cursor[c0+i] = 0; }
        if (t == (NNODES/CH)-1) rowptr[NNODES] = run;
    }
}

__global__ void __launch_bounds__(256) k_scatter(const int* __restrict__ ei_dst,
        const int* __restrict__ rowptr, int* __restrict__ cursor, int* __restrict__ perm){
    int e = blockIdx.x*256 + threadIdx.x;
    if (e >= NEDGES) return;
    int d = ei_dst[e];
    int pos = rowptr[d] + atomicAdd(&cursor[d], 1);
    perm[pos] = e;
}

// ---------------- per-step kernel 1: edge MLPs -> logits (MFMA fp16x3) ----------------
// Block = 256 edges = 4 waves, each wave fully owns 64 edges (no block barriers).
// phase1: thread-per-edge relu(h1) -> LDS (fp16 hi/lo rows, stride 72 halves).
// phase2: wave GEMM C[64x64] = A @ M via 96 mfma_f32_16x16x32_f16 (3-product split).
// phase3: thread-per-edge: logit = at_b2 + log(wflux+1e-8) + at_w2 . relu(C + G[src]).

__global__ void __launch_bounds__(256,2) k_edge_mfma(
    const float* __restrict__ xt, const float* __restrict__ G,
    const int* __restrict__ ei_src,
    const float* __restrict__ dist, const float* __restrict__ dirn,
    const float* __restrict__ ee_w1, const float* __restrict__ ee_b1,
    const _Float16* __restrict__ P_Mhi, const _Float16* __restrict__ P_Mlo,
    const float* __restrict__ at_w2, const float* __restrict__ at_b2,
    float* __restrict__ logits)
{
    __shared__ __align__(16) _Float16 smh[36864];   // A_hi [256][72] | A_lo [256][72]; reused for C
    float* smf = (float*)smh;

    const int tid = threadIdx.x;
    const int wv = tid>>6, lane = tid&63;
    const int e = blockIdx.x*256 + tid;

    // B fragments (M_hi/M_lo), coalesced 16B/lane loads
    f16x8 bh[4][2], bl[4][2];
    #pragma unroll
    for (int jt=0;jt<4;++jt){
        #pragma unroll
        for (int ks=0;ks<2;++ks){
            bh[jt][ks] = *(const f16x8*)(P_Mhi + (((jt*2+ks)*64 + lane)*8));
            bl[jt][ks] = *(const f16x8*)(P_Mlo + (((jt*2+ks)*64 + lane)*8));
        }
    }

    // ---- phase 1: per-edge features + relu(h1) -> LDS hi/lo ----
    const int src = ei_src[e];
    const float d  = dist[e];
    float2 dir2 = *reinterpret_cast<const float2*>(dirn + 2*e);
    float temp = xt[src*NFEAT+11];
    float4 q  = *reinterpret_cast<const float4*>(xt + src*NFEAT + 12); // sal,u,v,pad
    float flux = q.y*dir2.x + q.z*dir2.y;
    float wflux = fmaxf(flux, 0.f) * __expf(-d*(1.f/15.f));
    const float a0 = d, a1 = wflux, a2 = temp, a3 = q.x;
    const float lbias = at_b2[0] + __logf(wflux + 1e-8f);

    #pragma unroll
    for (int kb=0;kb<8;++kb){
        f16x8 hv, lv;
        #pragma unroll
        for (int i=0;i<8;++i){
            const int m = kb*8+i;
            float4 w1 = *reinterpret_cast<const float4*>(ee_w1 + m*4);  // uniform -> s_load
            float r = fmaxf(ee_b1[m] + a0*w1.x + a1*w1.y + a2*w1.z + a3*w1.w, 0.f);
            _Float16 hi = (_Float16)r;
            hv[i] = hi;
            lv[i] = (_Float16)(r - (float)hi);
        }
        *(f16x8*)(smh + tid*72 + kb*8)         = hv;
        *(f16x8*)(smh + 18432 + tid*72 + kb*8) = lv;
    }
    asm volatile("s_waitcnt lgkmcnt(0)" ::: "memory");

    // ---- phase 2: wave-local MFMA GEMM ----
    f32x4 c[4][4];
    #pragma unroll
    for (int et=0;et<4;++et)
        #pragma unroll
        for (int jt=0;jt<4;++jt)
            c[et][jt] = (f32x4){0.f,0.f,0.f,0.f};

    #pragma unroll
    for (int et=0;et<4;++et){
        #pragma unroll
        for (int ks=0;ks<2;++ks){
            const int row = wv*64 + et*16 + (lane&15);
            f16x8 ah = *(const f16x8*)(smh + row*72 + ks*32 + (lane>>4)*8);
            f16x8 al = *(const f16x8*)(smh + 18432 + row*72 + ks*32 + (lane>>4)*8);
            #pragma unroll
            for (int jt=0;jt<4;++jt){
                c[et][jt] = __builtin_amdgcn_mfma_f32_16x16x32_f16(ah, bh[jt][ks], c[et][jt], 0,0,0);
                c[et][jt] = __builtin_amdgcn_mfma_f32_16x16x32_f16(ah, bl[jt][ks], c[et][jt], 0,0,0);
                c[et][jt] = __builtin_amdgcn_mfma_f32_16x16x32_f16(al, bh[jt][ks], c[et][jt], 0,0,0);
            }
        }
    }
    asm volatile("s_waitcnt lgkmcnt(0)" ::: "memory");

    // ---- C -> LDS (re-use this wave's own A region; rows<32 -> A_hi part, rows>=32 -> A_lo part) ----
    // C layout: col = lane&15, row = (lane>>4)*4 + reg  (m89-verified)
    #pragma unroll
    for (int et=0;et<4;++et){
        #pragma unroll
        for (int jt=0;jt<4;++jt){
            #pragma unroll
            for (int i=0;i<4;++i){
                const int rl = et*16 + ((lane>>4)&3)*4 + i;
                const int col = jt*16 + (lane&15);
                const int idx = (et < 2) ? (wv*2304 + rl*68 + col)
                                         : (9216 + wv*2304 + (rl-32)*68 + col);
                smf[idx] = c[et][jt][i];
            }
        }
    }
    asm volatile("s_waitcnt lgkmcnt(0)" ::: "memory");

    // ---- phase 3: epilogue, thread-per-edge ----
    const int el = tid & 63;
    const float* crow = smf + ((el < 32) ? (wv*2304 + el*68)
                                         : (9216 + wv*2304 + (el-32)*68));
    const float4* G4 = reinterpret_cast<const float4*>(G + src*HDIM);
    float logit = lbias;
    #pragma unroll
    for (int jj=0;jj<16;++jj){
        float4 cv = *reinterpret_cast<const float4*>(crow + jj*4);
        float4 gv = G4[jj];
        float4 w4 = *reinterpret_cast<const float4*>(at_w2 + jj*4);   // uniform -> s_load
        logit += w4.x*fmaxf(cv.x+gv.x,0.f) + w4.y*fmaxf(cv.y+gv.y,0.f)
               + w4.z*fmaxf(cv.z+gv.z,0.f) + w4.w*fmaxf(cv.w+gv.w,0.f);
    }
    logits[e] = logit;
}

// ---------------- per-step kernel 2: segment softmax + pressure ----------------

__global__ void __launch_bounds__(256) k_softmax_pressure(
    const float* __restrict__ logits, const float* __restrict__ h,
    const float* __restrict__ lice, const int* __restrict__ ei_src,
    const int* __restrict__ rowptr, const int* __restrict__ perm,
    const float* __restrict__ log_beta,
    float* __restrict__ pressure)
{
    __shared__ float swgt[CAP];
    __shared__ int   ssrc[CAP];
    __shared__ float sred[4][64];
    __shared__ float sredm[4], sreds[4];

    const int node = blockIdx.x;
    const int tid = threadIdx.x;
    const int wid = tid >> 6;
    const int lane = tid & 63;
    const int start = rowptr[node], end = rowptr[node+1];
    const int deg = end - start;
    const int nfast = deg < CAP ? deg : CAP;

    float m = -INFINITY;
    for (int i=start+tid; i<end; i+=256){
        int e = perm[i];
        float lg = logits[e];
        int o = i - start;
        if (o < CAP){ swgt[o] = lg; ssrc[o] = ei_src[e]; }
        m = fmaxf(m, lg);
    }
    #pragma unroll
    for (int off=32; off>=1; off>>=1) m = fmaxf(m, __shfl_xor(m, off));
    if (lane == 0) sredm[wid] = m;
    __syncthreads();
    m = fmaxf(fmaxf(sredm[0], sredm[1]), fmaxf(sredm[2], sredm[3]));

    float s = 0.f;
    for (int i=start+tid; i<end; i+=256){
        int o = i - start;
        float lg = (o < CAP) ? swgt[o] : logits[perm[i]];
        s += __expf(lg - m);
    }
    #pragma unroll
    for (int off=32; off>=1; off>>=1) s += __shfl_xor(s, off);
    if (lane == 0) sreds[wid] = s;
    __syncthreads();
    s = (sreds[0]+sreds[1])+(sreds[2]+sreds[3]);

    const float binv = __expf(log_beta[0])/(s + 1e-8f);

    for (int o=tid; o<nfast; o+=256){
        int sc = ssrc[o];
        swgt[o] = __expf(swgt[o] - m) * binv * lice[sc*LDIM];
    }
    __syncthreads();

    float p = 0.f;
    for (int o=wid; o<nfast; o+=4)
        p += swgt[o]*h[ssrc[o]*HDIM + lane];
    for (int i=start+CAP+wid; i<end; i+=4){
        int e = perm[i];
        int sc = ei_src[e];
        float wg = __expf(logits[e]-m)*binv*lice[sc*LDIM];
        p += wg*h[sc*HDIM+lane];
    }
    sred[wid][lane] = p;
    __syncthreads();
    if (wid == 0)
        pressure[node*HDIM + lane] = (sred[0][lane]+sred[1][lane])+(sred[2][lane]+sred[3][lane]);
}

// ---------------- per-step kernel 3: node update + G projection ----------------
// 256 threads = 4 waves; 16 nodes/block, 4 nodes per wave (register-blocked).

#define NU2_THREADS 256
#define NU2_NPB 16

__global__ void __launch_bounds__(NU2_THREADS) k_node_update(
    const float* __restrict__ xt,
    float* __restrict__ h, float* __restrict__ lice,
    const float* __restrict__ pressure,
    const float* __restrict__ en_w1, const float* __restrict__ en_b1, const float* __restrict__ en_b2,
    const float* __restrict__ P_en, const float* __restrict__ P_wih, const float* __restrict__ P_whh,
    const float* __restrict__ P_de, const float* __restrict__ P_a2,
    const float* __restrict__ gru_bih, const float* __restrict__ gru_bhh,
    const float* __restrict__ de_b1, const float* __restrict__ de_w2, const float* __restrict__ de_b2,
    const float* __restrict__ cvec, const float* __restrict__ fec_t,
    const float* __restrict__ temp_sens,
    float* __restrict__ G, float* __restrict__ out_t)
{
    __shared__ float wbuf[8192];             // 32 KB phase-staged weights
    __shared__ float s_din[NU2_NPB][76];     // din (72 used), float4-aligned rows
    __shared__ float s_h[NU2_NPB][64];       // h, then hnew (in-place, wave-local)
    __shared__ float s_x[NU2_NPB][64];       // enc1 output t1

    const int tid = threadIdx.x;
    const int wv = tid>>6, lane = tid&63;
    const int nb = blockIdx.x*NU2_NPB;

    auto stage4 = [&](const float* __restrict__ src, int nfl, int dstoff){
        const float4* s4 = reinterpret_cast<const float4*>(src);
        float4* d4 = reinterpret_cast<float4*>(wbuf + dstoff);
        for (int i=tid; i<(nfl>>2); i+=NU2_THREADS) d4[i] = s4[i];
    };

    // ---- phase 0: gather per-node state (wave-local LDS) ----
    float hv[4], pm[4];
    #pragma unroll
    for (int m=0;m<4;++m){
        const int idx = wv*4+m, n = nb+idx;
        hv[m] = h[n*HDIM+lane];
        s_h[idx][lane] = hv[m];
        pm[m] = pressure[n*HDIM+lane];
        if (lane < 5)      s_din[idx][64+lane] = xt[n*NFEAT+11+lane];
        else if (lane < 8) s_din[idx][64+lane] = lice[n*LDIM + (lane-5)];
    }

    // ---- stage A: P_en + en_w1 ----
    stage4(P_en, 4096, 0);
    stage4(en_w1, 320, 4096);
    __syncthreads();

    // enc1 (5->64, relu)
    #pragma unroll
    for (int m=0;m<4;++m){
        const int idx = wv*4+m;
        float t1 = en_b1[lane];
        #pragma unroll
        for (int k=0;k<5;++k) t1 += s_din[idx][64+k]*wbuf[4096 + lane*5 + k];
        s_x[idx][lane] = fmaxf(t1, 0.f);
    }
    // enc2 (64->64) + pressure -> din
    float dinl[4];
    #pragma unroll
    for (int m=0;m<4;++m) dinl[m] = en_b2[lane] + pm[m];
    #pragma unroll 4
    for (int k4=0;k4<16;++k4){
        float4 w4 = *reinterpret_cast<const float4*>(&wbuf[(k4*64+lane)*4]);
        #pragma unroll
        for (int m=0;m<4;++m){
            float4 x4 = *reinterpret_cast<const float4*>(&s_x[wv*4+m][k4*4]);
            dinl[m] += x4.x*w4.x + x4.y*w4.y + x4.z*w4.z + x4.w*w4.w;
        }
    }
    #pragma unroll
    for (int m=0;m<4;++m) s_din[wv*4+m][lane] = dinl[m];
    __syncthreads();

    // ---- GRU input side: P_wih (18 k4) in 2 chunks of 9 ----
    float gi0[4], gi1[4], gi2[4];
    #pragma unroll
    for (int m=0;m<4;++m){
        gi0[m]=gru_bih[lane]; gi1[m]=gru_bih[64+lane]; gi2[m]=gru_bih[128+lane];
    }
    stage4(P_wih, 6912, 0);
    __syncthreads();
    #pragma unroll 3
    for (int k4=0;k4<9;++k4){
        const float* wp = &wbuf[(k4*64+lane)*12];
        float4 w0=*reinterpret_cast<const float4*>(wp);
        float4 w1=*reinterpret_cast<const float4*>(wp+4);
        float4 w2=*reinterpret_cast<const float4*>(wp+8);
        #pragma unroll
        for (int m=0;m<4;++m){
            float4 x4 = *reinterpret_cast<const float4*>(&s_din[wv*4+m][k4*4]);
            gi0[m] += x4.x*w0.x + x4.y*w0.y + x4.z*w0.z + x4.w*w0.w;
            gi1[m] += x4.x*w1.x + x4.y*w1.y + x4.z*w1.z + x4.w*w1.w;
            gi2[m] += x4.x*w2.x + x4.y*w2.y + x4.z*w2.z + x4.w*w2.w;
        }
    }
    __syncthreads();
    stage4(P_wih + 6912, 6912, 0);
    __syncthreads();
    #pragma unroll 3
    for (int k4=9;k4<18;++k4){
        const float* wp = &wbuf[((k4-9)*64+lane)*12];
        float4 w0=*reinterpret_cast<const float4*>(wp);
        float4 w1=*reinterpret_cast<const float4*>(wp+4);
        float4 w2=*reinterpret_cast<const float4*>(wp+8);
        #pragma unroll
        for (int m=0;m<4;++m){
            float4 x4 = *reinterpret_cast<const float4*>(&s_din[wv*4+m][k4*4]);
            gi0[m] += x4.x*w0.x + x4.y*w0.y + x4.z*w0.z + x4.w*w0.w;
            gi1[m] += x4.x*w1.x + x4.y*w1.y + x4.z*w1.z + x4.w*w1.w;
            gi2[m] += x4.x*w2.x + x4.y*w2.y + x4.z*w2.z + x4.w*w2.w;
        }
    }
    __syncthreads();

    // ---- GRU hidden side: P_whh (16 k4) in 2 chunks of 8 ----
    float gh0[4], gh1[4], gh2[4];
    #pragma unroll
    for (int m=0;m<4;++m){
        gh0[m]=gru_bhh[lane]; gh1[m]=gru_bhh[64+lane]; gh2[m]=gru_bhh[128+lane];
    }
    stage4(P_whh, 6144, 0);
    __syncthreads();
    #pragma unroll 3
    for (int k4=0;k4<8;++k4){
        const float* wp = &wbuf[(k4*64+lane)*12];
        float4 w0=*reinterpret_cast<const float4*>(wp);
        float4 w1=*reinterpret_cast<const float4*>(wp+4);
        float4 w2=*reinterpret_cast<const float4*>(wp+8);
        #pragma unroll
        for (int m=0;m<4;++m){
            float4 x4 = *reinterpret_cast<const float4*>(&s_h[wv*4+m][k4*4]);
            gh0[m] += x4.x*w0.x + x4.y*w0.y + x4.z*w0.z + x4.w*w0.w;
            gh1[m] += x4.x*w1.x + x4.y*w1.y + x4.z*w1.z + x4.w*w1.w;
            gh2[m] += x4.x*w2.x + x4.y*w2.y + x4.z*w2.z + x4.w*w2.w;
        }
    }
    __syncthreads();
    stage4(P_whh + 6144, 6144, 0);
    __syncthreads();
    #pragma unroll 3
    for (int k4=8;k4<16;++k4){
        const float* wp = &wbuf[((k4-8)*64+lane)*12];
        float4 w0=*reinterpret_cast<const float4*>(wp);
        float4 w1=*reinterpret_cast<const float4*>(wp+4);
        float4 w2=*reinterpret_cast<const float4*>(wp+8);
        #pragma unroll
        for (int m=0;m<4;++m){
            float4 x4 = *reinterpret_cast<const float4*>(&s_h[wv*4+m][k4*4]);
            gh0[m] += x4.x*w0.x + x4.y*w0.y + x4.z*w0.z + x4.w*w0.w;
            gh1[m] += x4.x*w1.x + x4.y*w1.y + x4.z*w1.z + x4.w*w1.w;
            gh2[m] += x4.x*w2.x + x4.y*w2.y + x4.z*w2.z + x4.w*w2.w;
        }
    }

    // ---- GRU glue; write hnew (global + in-place s_h, wave-local) ----
    #pragma unroll
    for (int m=0;m<4;++m){
        const int idx = wv*4+m, n = nb+idx;
        float r  = sigmoidf_(gi0[m] + gh0[m]);
        float z  = sigmoidf_(gi1[m] + gh1[m]);
        float nn = tanhf_(gi2[m] + r*gh2[m]);
        float hnew = (1.f - z)*nn + z*hv[m];
        h[n*HDIM+lane] = hnew;
        s_h[idx][lane] = hnew;
    }
    __syncthreads();

    // ---- stage D: P_de + P_a2 ----
    stage4(P_de, 4096, 0);
    stage4(P_a2, 4096, 4096);
    __syncthreads();

    // dec1 (64->64 relu) and G projection (cvec + hnew @ A2)
    float d1m[4], gv[4];
    #pragma unroll
    for (int m=0;m<4;++m){ d1m[m] = de_b1[lane]; gv[m] = cvec[lane]; }
    #pragma unroll 4
    for (int k4=0;k4<16;++k4){
        float4 wd = *reinterpret_cast<const float4*>(&wbuf[(k4*64+lane)*4]);
        float4 wa = *reinterpret_cast<const float4*>(&wbuf[4096 + (k4*64+lane)*4]);
        #pragma unroll
        for (int m=0;m<4;++m){
            float4 x4 = *reinterpret_cast<const float4*>(&s_h[wv*4+m][k4*4]);
            d1m[m] += x4.x*wd.x + x4.y*wd.y + x4.z*wd.z + x4.w*wd.w;
            gv[m]  += x4.x*wa.x + x4.y*wa.y + x4.z*wa.z + x4.w*wa.w;
        }
    }
    #pragma unroll
    for (int m=0;m<4;++m){
        const int n = nb+wv*4+m;
        G[n*HDIM+lane] = gv[m];
        d1m[m] = fmaxf(d1m[m], 0.f);
    }

    // dec2 (64->3) via shuffle reduce, then output
    #pragma unroll
    for (int m=0;m<4;++m){
        const int n = nb+wv*4+m;
        float s0 = d1m[m]*de_w2[lane];
        float s1 = d1m[m]*de_w2[64+lane];
        float s2 = d1m[m]*de_w2[128+lane];
        #pragma unroll
        for (int off=32; off>=1; off>>=1){
            s0 += __shfl_xor(s0, off);
            s1 += __shfl_xor(s1, off);
            s2 += __shfl_xor(s2, off);
        }
        float fec = fec_t[n];
        if (lane < LDIM){
            float oi = (lane==0 ? s0 : (lane==1 ? s1 : s2)) + de_b2[lane];
            float lb = softplusf_(oi);
            float ln = lb * (1.f + temp_sens[0]*(fec - 1.f));
            lice[n*LDIM+lane] = ln;
            out_t[n*LDIM+lane] = ln;
        }
    }
}

// ---------------- launcher ----------------

extern "C" void kernel_launch(void* const* d_in, const int* in_sizes, int n_in,
                              void* d_out, int out_size, void* d_ws, size_t ws_size,
                              hipStream_t stream) {
    const float* nfs       = (const float*)d_in[0];
    const float* init_lice = (const float*)d_in[1];
    const float* dist      = (const float*)d_in[2];
    const float* dirn      = (const float*)d_in[3];
    const float* ee_w1     = (const float*)d_in[4];
    const float* ee_b1     = (const float*)d_in[5];
    const float* ee_w2     = (const float*)d_in[6];
    const float* ee_b2     = (const float*)d_in[7];
    const float* at_w1     = (const float*)d_in[8];
    const float* at_b1     = (const float*)d_in[9];
    const float* at_w2     = (const float*)d_in[10];
    const float* at_b2     = (const float*)d_in[11];
    const float* en_w1     = (const float*)d_in[12];
    const float* en_b1     = (const float*)d_in[13];
    const float* en_w2     = (const float*)d_in[14];
    const float* en_b2     = (const float*)d_in[15];
    const float* fe_w1     = (const float*)d_in[16];
    const float* fe_b1     = (const float*)d_in[17];
    const float* fe_w2     = (const float*)d_in[18];
    const float* fe_b2     = (const float*)d_in[19];
    const float* fe_w3     = (const float*)d_in[20];
    const float* fe_b3     = (const float*)d_in[21];
    const float* gru_wih   = (const float*)d_in[22];
    const float* gru_whh   = (const float*)d_in[23];
    const float* gru_bih   = (const float*)d_in[24];
    const float* gru_bhh   = (const float*)d_in[25];
    const float* de_w1     = (const float*)d_in[26];
    const float* de_b1     = (const float*)d_in[27];
    const float* de_w2     = (const float*)d_in[28];
    const float* de_b2     = (const float*)d_in[29];
    const float* log_beta  = (const float*)d_in[30];
    const float* temp_sens = (const float*)d_in[31];
    const int*   ei        = (const int*)d_in[32];
    const int*   ei_src = ei;
    const int*   ei_dst = ei + NEDGES;
    float* out = (float*)d_out;

    // workspace carve (floats; keep offsets %4 for 16B alignment)
    float* wsf = (float*)d_ws;
    size_t off = 0;
    float* h        = wsf + off; off += (size_t)NNODES*HDIM;   // 640000
    float* lice     = wsf + off; off += (size_t)NNODES*LDIM + 2;
    off = (off + 3) & ~(size_t)3;
    float* logits   = wsf + off; off += (size_t)NEDGES;        // 320000
    float* pressure = wsf + off; off += (size_t)NNODES*HDIM;   // 640000
    float* G        = wsf + off; off += (size_t)NNODES*HDIM;   // 640000
    float* cvec     = wsf + off; off += 64;
    _Float16* P_Mhi = (_Float16*)(wsf + off); off += 2048;     // 4096 halves
    _Float16* P_Mlo = (_Float16*)(wsf + off); off += 2048;
    float* P_en     = wsf + off; off += 4096;
    float* P_wih    = wsf + off; off += 13824;
    float* P_whh    = wsf + off; off += 12288;
    float* P_de     = wsf + off; off += 4096;
    float* P_a2     = wsf + off; off += 4096;
    float* fec_arr  = wsf + off; off += (size_t)T_STEPS*NNODES; // 80000
    int* counts = (int*)(wsf + off); off += NNODES;
    int* rowptr = (int*)(wsf + off); off += NNODES+1;
    int* cursor = (int*)(wsf + off); off += NNODES;
    int* perm   = (int*)(wsf + off); off += NEDGES;

    // setup (k_prep first: k_init consumes cvec)
    k_prep<<<16,256,0,stream>>>(ee_w2, ee_b2, at_w1, at_b1, P_Mhi, P_Mlo, cvec);
    k_init<<<2500,256,0,stream>>>(init_lice, cvec, gru_wih, gru_whh, en_w2, de_w1, at_w1,
                                  h, lice, G, P_en, P_wih, P_whh, P_de, P_a2, counts);
    k_fec<<<(T_STEPS*NNODES+255)/256,256,0,stream>>>(nfs, fe_w1, fe_b1, fe_w2, fe_b2,
                                                     fe_w3, fe_b3, fec_arr);
    k_hist<<<1250,256,0,stream>>>(ei_dst, counts);
    k_scan<<<1,1024,0,stream>>>(counts, rowptr, cursor);
    k_scatter<<<1250,256,0,stream>>>(ei_dst, rowptr, cursor, perm);

    for (int t=0; t<T_STEPS; ++t){
        const float* xt = nfs + (size_t)t*NNODES*NFEAT;
        k_edge_mfma<<<1250,256,0,stream>>>(xt, G, ei_src, dist, dirn,
                                           ee_w1, ee_b1, P_Mhi, P_Mlo,
                                           at_w2, at_b2, logits);
        k_softmax_pressure<<<NNODES,256,0,stream>>>(logits, h, lice, ei_src,
                                                    rowptr, perm, log_beta, pressure);
        k_node_update<<<NNODES/NU2_NPB,NU2_THREADS,0,stream>>>(xt, h, lice, pressure,
                                             en_w1, en_b1, en_b2,
                                             P_en, P_wih, P_whh, P_de, P_a2,
                                             gru_bih, gru_bhh,
                                             de_b1, de_w2, de_b2,
                                             cvec, fec_arr + (size_t)t*NNODES,
                                             temp_sens,
                                             G, out + (size_t)t*NNODES*LDIM);
    }
}